// Round 5
// baseline (1046.318 us; speedup 1.0000x reference)
//
#include <hip/hip_runtime.h>
#include <hip/hip_bf16.h>

#define S_ 4096
#define D_ 1024
#define H_ 16
#define DK_ 64
#define F_ 4096
#define KSPLIT 4

typedef short bf16x8_t __attribute__((ext_vector_type(8)));
typedef float f32x4_t __attribute__((ext_vector_type(4)));

#define MFMA16(a, b, c) __builtin_amdgcn_mfma_f32_16x16x32_bf16(a, b, c, 0, 0, 0)

// q-scale: 1/sqrt(64) * log2(e)  (softmax done in base-2)
#define QSCALE 0.1803368801111243f

__device__ __forceinline__ short f2bf(float f) {
  union { float f; unsigned u; } a; a.f = f;
  unsigned r = a.u + 0x7fffu + ((a.u >> 16) & 1u);
  return (short)(r >> 16);
}
__device__ __forceinline__ float bf2f(short s) {
  union { unsigned u; float f; } a; a.u = ((unsigned)(unsigned short)s) << 16;
  return a.f;
}
__device__ __forceinline__ unsigned cvtpk_bf16(float lo, float hi) {
  unsigned w;
  asm("v_cvt_pk_bf16_f32 %0, %1, %2" : "=v"(w) : "v"(lo), "v"(hi));
  return w;
}

__device__ __forceinline__ void async_copy16(short* ldsDst, const short* gSrc) {
  __builtin_amdgcn_global_load_lds(
      (const __attribute__((address_space(1))) unsigned int*)gSrc,
      (__attribute__((address_space(3))) unsigned int*)ldsDst, 16, 0, 0);
}

// ---- weight prep: fp32 [K][N] (flat) or [H][K][64] (head) -> bf16 hi/lo in [N][K]
template<int HEADMODE>
__global__ __launch_bounds__(256)
void prep_w(const float* __restrict__ W, short* __restrict__ outHi,
            short* __restrict__ outLo, int K, int N) {
  __shared__ float t[32][33];
  int n0 = blockIdx.x * 32, k0 = blockIdx.y * 32;
  int tid = threadIdx.x;
  int cin = tid & 31, kin = tid >> 5;
#pragma unroll
  for (int i = 0; i < 4; ++i) {
    int k = kin + i * 8;
    int n = n0 + cin;
    long srcIdx;
    if (HEADMODE) srcIdx = ((long)(n >> 6) * K + (k0 + k)) * 64 + (n & 63);
    else          srcIdx = (long)(k0 + k) * N + n;
    t[k][cin] = W[srcIdx];
  }
  __syncthreads();
  int kout = tid & 31, cb = tid >> 5;
#pragma unroll
  for (int i = 0; i < 4; ++i) {
    int c = cb + i * 8;
    float v = t[kout][c];
    short hi = f2bf(v);
    short lo = f2bf(v - bf2f(hi));
    long dst = (long)(n0 + c) * K + (k0 + kout);
    outHi[dst] = hi;
    outLo[dst] = lo;
  }
}

// ---- fp32 -> bf16 hi/lo elementwise
__global__ __launch_bounds__(256)
void cvt_hl(const float* __restrict__ x, short* __restrict__ h, short* __restrict__ l) {
  long i = ((long)blockIdx.x * 256 + threadIdx.x) * 4;
  float4 v = *(const float4*)(x + i);
  short4 hh, ll;
  hh.x = f2bf(v.x); ll.x = f2bf(v.x - bf2f(hh.x));
  hh.y = f2bf(v.y); ll.y = f2bf(v.y - bf2f(hh.y));
  hh.z = f2bf(v.z); ll.z = f2bf(v.z - bf2f(hh.z));
  hh.w = f2bf(v.w); ll.w = f2bf(v.w - bf2f(hh.w));
  *(short4*)(h + i) = hh;
  *(short4*)(l + i) = ll;
}

// ---- bf16x3 GEMM, 128x128 tile, BK=32, global_load_lds staging, swizzled LDS
#define EPI_QKV 0
#define EPI_PART 1
#define EPI_RELUHL 2

template<int EPI, int SPLITK>
__global__ __launch_bounds__(256)
void gemm_bf3(const short* __restrict__ AH, const short* __restrict__ AL,
              const short* __restrict__ BH, const short* __restrict__ BL,
              int K, int M, int N,
              const float* __restrict__ bq_, const float* __restrict__ bk_,
              const float* __restrict__ bv_,
              void* __restrict__ out0, void* __restrict__ out1) {
  __shared__ short lds[16384];  // 32 KB: AH|AL|BH|BL panels, each [128][32]
  const int m0 = blockIdx.x * 128, n0 = blockIdx.y * 128;
  const int tid = threadIdx.x;
  const int wave = tid >> 6, lane = tid & 63;
  const int wr = wave >> 1, wc = wave & 1;
  const int lg = lane >> 4, lr = lane & 15;
  const int kLen = (SPLITK > 1) ? (K / SPLITK) : K;
  const long kBase = (SPLITK > 1) ? (long)blockIdx.z * kLen : 0;
  const int nk = kLen >> 5;

  const short* gAH = AH + (long)m0 * K + kBase;
  const short* gAL = AL + (long)m0 * K + kBase;
  const short* gBH = BH + (long)n0 * K + kBase;
  const short* gBL = BL + (long)n0 * K + kBase;

  f32x4_t acc[4][4];
#pragma unroll
  for (int i = 0; i < 4; ++i)
#pragma unroll
    for (int j = 0; j < 4; ++j)
      acc[i][j] = (f32x4_t){0.f, 0.f, 0.f, 0.f};

  for (int kt = 0; kt < nk; ++kt) {
    // stage 4 panels via global_load_lds (linear LDS, pre-swizzled global source)
#pragma unroll
    for (int p = 0; p < 8; ++p) {
      const short* gb = (p < 2) ? gAH : (p < 4) ? gAL : (p < 6) ? gBH : gBL;
      int w = ((p & 1) << 8) | tid;
      int row = w >> 2;
      int gsw = ((w & 3) ^ (row & 3)) << 3;  // XOR granule swizzle
      async_copy16(lds + (((p << 8) | tid) << 3),
                   gb + (long)row * K + (kt << 5) + gsw);
    }
    __syncthreads();
    bf16x8_t ah[4], al[4], bh[4], bl[4];
#pragma unroll
    for (int f = 0; f < 4; ++f) {
      int ar = wr * 64 + f * 16 + lr;
      int ag = (lg ^ (ar & 3)) << 3;
      ah[f] = *(const bf16x8_t*)(lds + ar * 32 + ag);
      al[f] = *(const bf16x8_t*)(lds + 4096 + ar * 32 + ag);
      int br = wc * 64 + f * 16 + lr;
      int bg = (lg ^ (br & 3)) << 3;
      bh[f] = *(const bf16x8_t*)(lds + 8192 + br * 32 + bg);
      bl[f] = *(const bf16x8_t*)(lds + 12288 + br * 32 + bg);
    }
#pragma unroll
    for (int i = 0; i < 4; ++i)
#pragma unroll
      for (int j = 0; j < 4; ++j) {
        acc[i][j] = MFMA16(ah[i], bh[j], acc[i][j]);
        acc[i][j] = MFMA16(ah[i], bl[j], acc[i][j]);
        acc[i][j] = MFMA16(al[i], bh[j], acc[i][j]);
      }
    __syncthreads();
  }

  // epilogue: C row = mB + r, col = n
#pragma unroll
  for (int i = 0; i < 4; ++i) {
    int mB = m0 + wr * 64 + i * 16 + lg * 4;
#pragma unroll
    for (int j = 0; j < 4; ++j) {
      int n = n0 + wc * 64 + j * 16 + lr;
      if constexpr (EPI == EPI_PART) {
        float* outp = (float*)out0 + (long)blockIdx.z * M * N;
#pragma unroll
        for (int r = 0; r < 4; ++r)
          outp[(long)(mB + r) * N + n] = acc[i][j][r];
      } else if constexpr (EPI == EPI_RELUHL) {
        float bs = bq_[n];
        short* oH = (short*)out0;
        short* oL = (short*)out1;
#pragma unroll
        for (int r = 0; r < 4; ++r) {
          float v = fmaxf(acc[i][j][r] + bs, 0.f);
          short hi = f2bf(v);
          long idx = (long)(mB + r) * N + n;
          oH[idx] = hi;
          oL[idx] = f2bf(v - bf2f(hi));
        }
      } else {  // EPI_QKV: q|k -> qk[S][2048] (q scaled QSCALE), v -> vT[1024][S]
        short* qko = (short*)out0;
        short* vto = (short*)out1;
        if (n < 1024) {
          float bs = bq_[n];
#pragma unroll
          for (int r = 0; r < 4; ++r)
            qko[(long)(mB + r) * 2048 + n] = f2bf((acc[i][j][r] + bs) * QSCALE);
        } else if (n < 2048) {
          float bs = bk_[n - 1024];
#pragma unroll
          for (int r = 0; r < 4; ++r)
            qko[(long)(mB + r) * 2048 + n] = f2bf(acc[i][j][r] + bs);
        } else {
          float bs = bv_[n - 2048];
          short4 pk;
          pk.x = f2bf(acc[i][j][0] + bs);
          pk.y = f2bf(acc[i][j][1] + bs);
          pk.z = f2bf(acc[i][j][2] + bs);
          pk.w = f2bf(acc[i][j][3] + bs);
          *(short4*)(vto + (long)(n - 2048) * S_ + mB) = pk;
        }
      }
    }
  }
}

// ---- flash attention, split-KV: grid (S/128, H, KSPLIT), 4 waves x 32 q-rows.
// Each block handles S/KSPLIT kv positions, writes unnormalized partial O (fp32)
// + per-q (m, l) in log2 domain. S' = mfma(K,Q): lane holds q = lane&15,
// kv = 16*kc + 4*(lane>>4) + r -> softmax reg-local (15 fmax) + 2 shfl_xor.
// P -> per-wave LDS -> ds_read_b128 B-frags. PV: O^T = mfma(V^T, P).
// Defer-max (THR=8), reg-dbuf K, V prefetch under softmax, setprio on MFMA.
__global__ __launch_bounds__(256, 4)
void attn_part(const short* __restrict__ qk, const short* __restrict__ vT,
               float* __restrict__ Opart, float* __restrict__ mlb) {
  __shared__ short plds[4][32][72];  // per-wave P tile, stride 144B
  const int qt = blockIdx.x, h = blockIdx.y, z = blockIdx.z;
  const int tid = threadIdx.x;
  const int wave = tid >> 6, lane = tid & 63;
  const int lg = lane >> 4, lr = lane & 15;
  const int qrow0 = qt * 128 + wave * 32;
  const int ktBeg = z * (S_ / 64 / KSPLIT);
  const int ktEnd = ktBeg + S_ / 64 / KSPLIT;

  const short* qh = qk + (long)qrow0 * 2048 + h * 64;
  const short* kh = qk + 1024 + h * 64;
  const short* vh = vT + (long)h * 64 * S_;

  // Q as B-operand frags: Q[qb*16+lr][di*32 + lg*8 + j]
  bf16x8_t qf[2][2];
#pragma unroll
  for (int qb = 0; qb < 2; ++qb)
#pragma unroll
    for (int di = 0; di < 2; ++di)
      qf[qb][di] = *(const bf16x8_t*)(qh + (long)(qb * 16 + lr) * 2048 + di * 32 + lg * 8);

  float m[2] = {-1e30f, -1e30f}, l[2] = {0.f, 0.f};
  f32x4_t o[2][4];
#pragma unroll
  for (int qb = 0; qb < 2; ++qb)
#pragma unroll
    for (int dd = 0; dd < 4; ++dd) o[qb][dd] = (f32x4_t){0.f, 0.f, 0.f, 0.f};

  auto loadK = [&](bf16x8_t (&kf)[8], int kt) {
    const short* kb = kh + (long)kt * 64 * 2048;
#pragma unroll
    for (int kc = 0; kc < 4; ++kc)
#pragma unroll
      for (int di = 0; di < 2; ++di)
        kf[kc * 2 + di] =
            *(const bf16x8_t*)(kb + (long)(kc * 16 + lr) * 2048 + di * 32 + lg * 8);
  };

  auto step = [&](int kt, bf16x8_t (&kf)[8], bf16x8_t (&kn)[8]) {
    // V prefetch (used after softmax)
    bf16x8_t vf[8];
#pragma unroll
    for (int dd = 0; dd < 4; ++dd)
#pragma unroll
      for (int ks = 0; ks < 2; ++ks)
        vf[dd * 2 + ks] = *(const bf16x8_t*)(vh + (long)(dd * 16 + lr) * S_ +
                                             kt * 64 + ks * 32 + lg * 8);
    // S' = K.Q (swapped): 16 MFMA
    f32x4_t sacc[2][4];
#pragma unroll
    for (int qb = 0; qb < 2; ++qb)
#pragma unroll
      for (int kc = 0; kc < 4; ++kc) sacc[qb][kc] = (f32x4_t){0.f, 0.f, 0.f, 0.f};
    __builtin_amdgcn_s_setprio(1);
#pragma unroll
    for (int kc = 0; kc < 4; ++kc)
#pragma unroll
      for (int qb = 0; qb < 2; ++qb) {
        sacc[qb][kc] = MFMA16(kf[kc * 2 + 0], qf[qb][0], sacc[qb][kc]);
        sacc[qb][kc] = MFMA16(kf[kc * 2 + 1], qf[qb][1], sacc[qb][kc]);
      }
    __builtin_amdgcn_s_setprio(0);
    // prefetch next K tile (latency hidden under softmax + P-LDS)
    if (kt + 1 < ktEnd) loadK(kn, kt + 1);

    // softmax (per lane: one q-column, 16 kv values per qb)
#pragma unroll
    for (int qb = 0; qb < 2; ++qb) {
      float p01 = fmaxf(fmaxf(sacc[qb][0][0], sacc[qb][0][1]),
                        fmaxf(sacc[qb][0][2], sacc[qb][0][3]));
      float p23 = fmaxf(fmaxf(sacc[qb][1][0], sacc[qb][1][1]),
                        fmaxf(sacc[qb][1][2], sacc[qb][1][3]));
      float p45 = fmaxf(fmaxf(sacc[qb][2][0], sacc[qb][2][1]),
                        fmaxf(sacc[qb][2][2], sacc[qb][2][3]));
      float p67 = fmaxf(fmaxf(sacc[qb][3][0], sacc[qb][3][1]),
                        fmaxf(sacc[qb][3][2], sacc[qb][3][3]));
      float pmax = fmaxf(fmaxf(p01, p23), fmaxf(p45, p67));
      pmax = fmaxf(pmax, __shfl_xor(pmax, 16));
      pmax = fmaxf(pmax, __shfl_xor(pmax, 32));
      if (!__all(pmax <= m[qb] + 8.0f)) {  // defer-max: rescale rarely fires
        float ef = exp2f(m[qb] - pmax);
        m[qb] = pmax;
        l[qb] *= ef;
#pragma unroll
        for (int dd = 0; dd < 4; ++dd) o[qb][dd] *= ef;
      }
      float mq = m[qb];
      float rsum = 0.f;
#pragma unroll
      for (int kc = 0; kc < 4; ++kc) {
        float e0 = exp2f(sacc[qb][kc][0] - mq);
        float e1 = exp2f(sacc[qb][kc][1] - mq);
        float e2 = exp2f(sacc[qb][kc][2] - mq);
        float e3 = exp2f(sacc[qb][kc][3] - mq);
        rsum += (e0 + e1) + (e2 + e3);
        uint2 w;
        w.x = cvtpk_bf16(e0, e1);
        w.y = cvtpk_bf16(e2, e3);
        *(uint2*)&plds[wave][qb * 16 + lr][kc * 16 + lg * 4] = w;
      }
      rsum += __shfl_xor(rsum, 16);
      rsum += __shfl_xor(rsum, 32);
      l[qb] += rsum;
    }
    // P back as B-frags: P^T rows q=lr, kv contiguous
    bf16x8_t pb[2][2];
#pragma unroll
    for (int qb = 0; qb < 2; ++qb)
#pragma unroll
      for (int ks = 0; ks < 2; ++ks)
        pb[qb][ks] = *(const bf16x8_t*)&plds[wave][qb * 16 + lr][ks * 32 + lg * 8];
    // O^T += V^T . P : 16 MFMA
    __builtin_amdgcn_s_setprio(1);
#pragma unroll
    for (int dd = 0; dd < 4; ++dd)
#pragma unroll
      for (int qb = 0; qb < 2; ++qb) {
        o[qb][dd] = MFMA16(vf[dd * 2 + 0], pb[qb][0], o[qb][dd]);
        o[qb][dd] = MFMA16(vf[dd * 2 + 1], pb[qb][1], o[qb][dd]);
      }
    __builtin_amdgcn_s_setprio(0);
  };

  bf16x8_t k0f[8], k1f[8];
  loadK(k0f, ktBeg);
  for (int kt = ktBeg; kt < ktEnd; kt += 2) {
    step(kt, k0f, k1f);
    step(kt + 1, k1f, k0f);
  }

  // store unnormalized partial O (fp32 float4) + (m,l) per q-row
#pragma unroll
  for (int qb = 0; qb < 2; ++qb) {
    int q = qrow0 + qb * 16 + lr;
    long qbase = ((long)(z * H_ + h) * S_ + q) * 64;
#pragma unroll
    for (int dd = 0; dd < 4; ++dd) {
      float4 v = {o[qb][dd][0], o[qb][dd][1], o[qb][dd][2], o[qb][dd][3]};
      *(float4*)(Opart + qbase + dd * 16 + lg * 4) = v;
    }
    if (lg == 0) {
      float2 mlv = {m[qb], l[qb]};
      *(float2*)(mlb + ((long)(z * H_ + h) * S_ + q) * 2) = mlv;
    }
  }
}

// ---- merge KSPLIT partials: out = (sum_z w_z O_z) / (sum_z w_z l_z), w=2^(m_z-M)
__global__ __launch_bounds__(256)
void attn_merge(const float* __restrict__ Opart, const float* __restrict__ mlb,
                short* __restrict__ attnH, short* __restrict__ attnL) {
  int idx = blockIdx.x * 256 + threadIdx.x;  // H * S * 16 threads
  int h = idx >> 16;
  int rem = idx & 65535;
  int q = rem >> 4;
  int dg = rem & 15;

  float mz[KSPLIT], lz[KSPLIT];
  float M = -1e30f;
#pragma unroll
  for (int z = 0; z < KSPLIT; ++z) {
    float2 mlv = *(const float2*)(mlb + ((long)(z * H_ + h) * S_ + q) * 2);
    mz[z] = mlv.x;
    lz[z] = mlv.y;
    M = fmaxf(M, mz[z]);
  }
  float L = 0.f;
  float4 O = {0.f, 0.f, 0.f, 0.f};
#pragma unroll
  for (int z = 0; z < KSPLIT; ++z) {
    float w = exp2f(mz[z] - M);
    L += w * lz[z];
    float4 ov = *(const float4*)(Opart + ((long)(z * H_ + h) * S_ + q) * 64 + dg * 4);
    O.x += w * ov.x;
    O.y += w * ov.y;
    O.z += w * ov.z;
    O.w += w * ov.w;
  }
  float inv = 1.0f / L;
  long base = (long)q * D_ + h * 64 + dg * 4;
  short4 hh, ll;
  float v0 = O.x * inv; hh.x = f2bf(v0); ll.x = f2bf(v0 - bf2f(hh.x));
  float v1 = O.y * inv; hh.y = f2bf(v1); ll.y = f2bf(v1 - bf2f(hh.y));
  float v2 = O.z * inv; hh.z = f2bf(v2); ll.z = f2bf(v2 - bf2f(hh.z));
  float v3 = O.w * inv; hh.w = f2bf(v3); ll.w = f2bf(v3 - bf2f(hh.w));
  *(short4*)(attnH + base) = hh;
  *(short4*)(attnL + base) = ll;
}

// ---- fused: x = pA + pB + res + bias; LayerNorm; optional hi/lo bf16 outputs
template<int WHL>
__global__ __launch_bounds__(256)
void ln_fused(const float* __restrict__ pA, const float* __restrict__ pB,
              const float* __restrict__ res, const float* __restrict__ bias,
              const float* __restrict__ g, const float* __restrict__ b,
              float* __restrict__ outF, short* __restrict__ outH,
              short* __restrict__ outL) {
  __shared__ float red[8];
  const int row = blockIdx.x, tid = threadIdx.x;
  const long base = (long)row * D_ + tid * 4;
  float4 a = *(const float4*)(pA + base);
  float4 c = *(const float4*)(pB + base);
  float4 rr = *(const float4*)(res + base);
  float4 bb = *(const float4*)(bias + tid * 4);
  float x0 = a.x + c.x + rr.x + bb.x;
  float x1v = a.y + c.y + rr.y + bb.y;
  float x2v = a.z + c.z + rr.z + bb.z;
  float x3v = a.w + c.w + rr.w + bb.w;
  float s = x0 + x1v + x2v + x3v;
  float s2 = x0 * x0 + x1v * x1v + x2v * x2v + x3v * x3v;
#pragma unroll
  for (int m = 1; m < 64; m <<= 1) {
    s += __shfl_xor(s, m);
    s2 += __shfl_xor(s2, m);
  }
  int wave = tid >> 6, lane = tid & 63;
  if (lane == 0) { red[wave * 2] = s; red[wave * 2 + 1] = s2; }
  __syncthreads();
  s = red[0] + red[2] + red[4] + red[6];
  s2 = red[1] + red[3] + red[5] + red[7];
  float mu = s * (1.f / D_);
  float var = s2 * (1.f / D_) - mu * mu;
  float rs = rsqrtf(var + 1e-5f);
  float4 gv = *(const float4*)(g + tid * 4);
  float4 bv = *(const float4*)(b + tid * 4);
  float y0 = (x0 - mu) * rs * gv.x + bv.x;
  float y1 = (x1v - mu) * rs * gv.y + bv.y;
  float y2 = (x2v - mu) * rs * gv.z + bv.z;
  float y3 = (x3v - mu) * rs * gv.w + bv.w;
  float4 ov = {y0, y1, y2, y3};
  *(float4*)(outF + base) = ov;
  if constexpr (WHL) {
    short4 hh, ll;
    hh.x = f2bf(y0); ll.x = f2bf(y0 - bf2f(hh.x));
    hh.y = f2bf(y1); ll.y = f2bf(y1 - bf2f(hh.y));
    hh.z = f2bf(y2); ll.z = f2bf(y2 - bf2f(hh.z));
    hh.w = f2bf(y3); ll.w = f2bf(y3 - bf2f(hh.w));
    *(short4*)(outH + base) = hh;
    *(short4*)(outL + base) = ll;
  }
}

extern "C" void kernel_launch(void* const* d_in, const int* in_sizes, int n_in,
                              void* d_out, int out_size, void* d_ws, size_t ws_size,
                              hipStream_t stream) {
  const float* src  = (const float*)d_in[0];
  const float* Wq   = (const float*)d_in[1];
  const float* bq   = (const float*)d_in[2];
  const float* Wk   = (const float*)d_in[3];
  const float* bk   = (const float*)d_in[4];
  const float* Wv   = (const float*)d_in[5];
  const float* bv   = (const float*)d_in[6];
  const float* Wo   = (const float*)d_in[7];
  const float* bo   = (const float*)d_in[8];
  const float* ln1g = (const float*)d_in[9];
  const float* ln1b = (const float*)d_in[10];
  const float* W1   = (const float*)d_in[11];
  const float* b1   = (const float*)d_in[12];
  const float* W2   = (const float*)d_in[13];
  const float* b2   = (const float*)d_in[14];
  const float* ln2g = (const float*)d_in[15];
  const float* ln2b = (const float*)d_in[16];
  float* out = (float*)d_out;

  const size_t SD = (size_t)S_ * D_;
  const size_t SF = (size_t)S_ * F_;

  char* w = (char*)d_ws;
  auto take = [&](size_t bytes) {
    char* p = w;
    w += (bytes + 255) & ~(size_t)255;
    return p;
  };
  // region A (aliased by W2 partials after attention is done):
  short* srcH  = (short*)take(SD * 2);
  short* srcL  = (short*)take(SD * 2);
  short* qkb   = (short*)take((size_t)S_ * 2048 * 2);
  short* vTb   = (short*)take((size_t)D_ * S_ * 2);
  // region B (Opart during attention; Wo partials after; h1 after LN1):
  short* h1H   = (short*)take(SF * 2);
  short* h1L   = (short*)take(SF * 2);
  // weights
  short* wqkvH = (short*)take((size_t)3072 * D_ * 2);
  short* wqkvL = (short*)take((size_t)3072 * D_ * 2);
  short* woH   = (short*)take((size_t)D_ * D_ * 2);
  short* woL   = (short*)take((size_t)D_ * D_ * 2);
  short* w1H   = (short*)take((size_t)F_ * D_ * 2);
  short* w1L   = (short*)take((size_t)F_ * D_ * 2);
  short* w2H   = (short*)take((size_t)D_ * F_ * 2);
  short* w2L   = (short*)take((size_t)D_ * F_ * 2);
  // activations
  short* attnH = (short*)take(SD * 2);
  short* attnL = (short*)take(SD * 2);
  float* x1    = (float*)take(SD * 4);
  short* x1H   = (short*)take(SD * 2);
  short* x1L   = (short*)take(SD * 2);

  float* Opart  = (float*)h1H;   // KSPLIT*H*S*64 fp32 = 67 MB = h1H+h1L exactly
  float* mlb    = (float*)x1H;   // KSPLIT*H*S*2 fp32 = 2 MB (x1H written later)
  float* partWo = (float*)h1H;   // 2*SD fp32 = 33.5 MB (after merge, Opart dead)
  float* partW2 = (float*)srcH;  // 2*SD fp32 spans srcH+srcL+qkb, all dead by then

  dim3 blk(256);

  // weight prep (transpose + hi/lo split); QKV into one [3072][1024] buffer
  prep_w<1><<<dim3(32, 32), blk, 0, stream>>>(Wq, wqkvH, wqkvL, D_, D_);
  prep_w<1><<<dim3(32, 32), blk, 0, stream>>>(Wk, wqkvH + (size_t)1024 * D_,
                                              wqkvL + (size_t)1024 * D_, D_, D_);
  prep_w<1><<<dim3(32, 32), blk, 0, stream>>>(Wv, wqkvH + (size_t)2048 * D_,
                                              wqkvL + (size_t)2048 * D_, D_, D_);
  prep_w<0><<<dim3(32, 32), blk, 0, stream>>>(Wo, woH, woL, D_, D_);
  prep_w<0><<<dim3(128, 32), blk, 0, stream>>>(W1, w1H, w1L, D_, F_);
  prep_w<0><<<dim3(32, 128), blk, 0, stream>>>(W2, w2H, w2L, F_, D_);

  // src -> hi/lo
  cvt_hl<<<dim3(4096), blk, 0, stream>>>(src, srcH, srcL);

  // fused QKV projection (q pre-scaled by QSCALE, v transposed per head)
  gemm_bf3<EPI_QKV, 1><<<dim3(32, 24), blk, 0, stream>>>(
      srcH, srcL, wqkvH, wqkvL, D_, S_, 3072, bq, bk, bv, qkb, vTb);

  // flash attention, split-KV -> merge -> attn hi/lo [S][1024]
  attn_part<<<dim3(32, 16, KSPLIT), blk, 0, stream>>>(qkb, vTb, Opart, mlb);
  attn_merge<<<dim3(H_ * S_ * 16 / 256), blk, 0, stream>>>(Opart, mlb, attnH, attnL);

  // Wo projection, split-K=2 partials; LN1 fuses partials + src + bo
  gemm_bf3<EPI_PART, 2><<<dim3(32, 8, 2), blk, 0, stream>>>(
      attnH, attnL, woH, woL, D_, S_, D_, nullptr, nullptr, nullptr, partWo, nullptr);
  ln_fused<1><<<dim3(S_), blk, 0, stream>>>(partWo, partWo + SD, src, bo,
                                            ln1g, ln1b, x1, x1H, x1L);

  // FFN
  gemm_bf3<EPI_RELUHL, 1><<<dim3(32, 32), blk, 0, stream>>>(
      x1H, x1L, w1H, w1L, D_, S_, F_, b1, nullptr, nullptr, h1H, h1L);
  gemm_bf3<EPI_PART, 2><<<dim3(32, 8, 2), blk, 0, stream>>>(
      h1H, h1L, w2H, w2L, F_, S_, D_, nullptr, nullptr, nullptr, partW2, nullptr);
  ln_fused<0><<<dim3(S_), blk, 0, stream>>>(partW2, partW2 + SD, x1, b2,
                                            ln2g, ln2b, out, nullptr, nullptr);

  (void)in_sizes; (void)n_in; (void)out_size; (void)ws_size;
}

// Round 6
// 652.682 us; speedup vs baseline: 1.6031x; 1.6031x over previous
//
#include <hip/hip_runtime.h>
#include <hip/hip_bf16.h>

#define S_ 4096
#define D_ 1024
#define H_ 16
#define DK_ 64
#define F_ 4096

typedef short bf16x8_t __attribute__((ext_vector_type(8)));
typedef float f32x4_t __attribute__((ext_vector_type(4)));

#define MFMA16(a, b, c) __builtin_amdgcn_mfma_f32_16x16x32_bf16(a, b, c, 0, 0, 0)

// q-scale: 1/sqrt(64) * log2(e)  (softmax done in base-2)
#define QSCALE 0.1803368801111243f

__device__ __forceinline__ short f2bf(float f) {
  union { float f; unsigned u; } a; a.f = f;
  unsigned r = a.u + 0x7fffu + ((a.u >> 16) & 1u);
  return (short)(r >> 16);
}
__device__ __forceinline__ float bf2f(short s) {
  union { unsigned u; float f; } a; a.u = ((unsigned)(unsigned short)s) << 16;
  return a.f;
}
__device__ __forceinline__ unsigned cvtpk_bf16(float lo, float hi) {
  unsigned w;
  asm("v_cvt_pk_bf16_f32 %0, %1, %2" : "=v"(w) : "v"(lo), "v"(hi));
  return w;
}

__device__ __forceinline__ void async_copy16(short* ldsDst, const short* gSrc) {
  __builtin_amdgcn_global_load_lds(
      (const __attribute__((address_space(1))) unsigned int*)gSrc,
      (__attribute__((address_space(3))) unsigned int*)ldsDst, 16, 0, 0);
}

// ---- weight prep: fp32 [K][N] (flat) or [H][K][64] (head) -> bf16 hi/lo in [N][K]
template<int HEADMODE>
__global__ __launch_bounds__(256)
void prep_w(const float* __restrict__ W, short* __restrict__ outHi,
            short* __restrict__ outLo, int K, int N) {
  __shared__ float t[32][33];
  int n0 = blockIdx.x * 32, k0 = blockIdx.y * 32;
  int tid = threadIdx.x;
  int cin = tid & 31, kin = tid >> 5;
#pragma unroll
  for (int i = 0; i < 4; ++i) {
    int k = kin + i * 8;
    int n = n0 + cin;
    long srcIdx;
    if (HEADMODE) srcIdx = ((long)(n >> 6) * K + (k0 + k)) * 64 + (n & 63);
    else          srcIdx = (long)(k0 + k) * N + n;
    t[k][cin] = W[srcIdx];
  }
  __syncthreads();
  int kout = tid & 31, cb = tid >> 5;
#pragma unroll
  for (int i = 0; i < 4; ++i) {
    int c = cb + i * 8;
    float v = t[kout][c];
    short hi = f2bf(v);
    short lo = f2bf(v - bf2f(hi));
    long dst = (long)(n0 + c) * K + (k0 + kout);
    outHi[dst] = hi;
    outLo[dst] = lo;
  }
}

// ---- fp32 -> bf16 hi/lo elementwise
__global__ __launch_bounds__(256)
void cvt_hl(const float* __restrict__ x, short* __restrict__ h, short* __restrict__ l) {
  long i = ((long)blockIdx.x * 256 + threadIdx.x) * 4;
  float4 v = *(const float4*)(x + i);
  short4 hh, ll;
  hh.x = f2bf(v.x); ll.x = f2bf(v.x - bf2f(hh.x));
  hh.y = f2bf(v.y); ll.y = f2bf(v.y - bf2f(hh.y));
  hh.z = f2bf(v.z); ll.z = f2bf(v.z - bf2f(hh.z));
  hh.w = f2bf(v.w); ll.w = f2bf(v.w - bf2f(hh.w));
  *(short4*)(h + i) = hh;
  *(short4*)(l + i) = ll;
}

// ---- bf16x3 GEMM, 128x128 tile, BK=32, global_load_lds staging, swizzled LDS
#define EPI_QKV 0
#define EPI_PART 1
#define EPI_RELUHL 2

template<int EPI, int SPLITK>
__global__ __launch_bounds__(256)
void gemm_bf3(const short* __restrict__ AH, const short* __restrict__ AL,
              const short* __restrict__ BH, const short* __restrict__ BL,
              int K, int M, int N,
              const float* __restrict__ bq_, const float* __restrict__ bk_,
              const float* __restrict__ bv_,
              void* __restrict__ out0, void* __restrict__ out1) {
  __shared__ short lds[16384];  // 32 KB: AH|AL|BH|BL panels, each [128][32]
  const int m0 = blockIdx.x * 128, n0 = blockIdx.y * 128;
  const int tid = threadIdx.x;
  const int wave = tid >> 6, lane = tid & 63;
  const int wr = wave >> 1, wc = wave & 1;
  const int lg = lane >> 4, lr = lane & 15;
  const int kLen = (SPLITK > 1) ? (K / SPLITK) : K;
  const long kBase = (SPLITK > 1) ? (long)blockIdx.z * kLen : 0;
  const int nk = kLen >> 5;

  const short* gAH = AH + (long)m0 * K + kBase;
  const short* gAL = AL + (long)m0 * K + kBase;
  const short* gBH = BH + (long)n0 * K + kBase;
  const short* gBL = BL + (long)n0 * K + kBase;

  f32x4_t acc[4][4];
#pragma unroll
  for (int i = 0; i < 4; ++i)
#pragma unroll
    for (int j = 0; j < 4; ++j)
      acc[i][j] = (f32x4_t){0.f, 0.f, 0.f, 0.f};

  for (int kt = 0; kt < nk; ++kt) {
    // stage 4 panels via global_load_lds (linear LDS, pre-swizzled global source)
#pragma unroll
    for (int p = 0; p < 8; ++p) {
      const short* gb = (p < 2) ? gAH : (p < 4) ? gAL : (p < 6) ? gBH : gBL;
      int w = ((p & 1) << 8) | tid;
      int row = w >> 2;
      int gsw = ((w & 3) ^ (row & 3)) << 3;  // XOR granule swizzle
      async_copy16(lds + (((p << 8) | tid) << 3),
                   gb + (long)row * K + (kt << 5) + gsw);
    }
    __syncthreads();
    bf16x8_t ah[4], al[4], bh[4], bl[4];
#pragma unroll
    for (int f = 0; f < 4; ++f) {
      int ar = wr * 64 + f * 16 + lr;
      int ag = (lg ^ (ar & 3)) << 3;
      ah[f] = *(const bf16x8_t*)(lds + ar * 32 + ag);
      al[f] = *(const bf16x8_t*)(lds + 4096 + ar * 32 + ag);
      int br = wc * 64 + f * 16 + lr;
      int bg = (lg ^ (br & 3)) << 3;
      bh[f] = *(const bf16x8_t*)(lds + 8192 + br * 32 + bg);
      bl[f] = *(const bf16x8_t*)(lds + 12288 + br * 32 + bg);
    }
#pragma unroll
    for (int i = 0; i < 4; ++i)
#pragma unroll
      for (int j = 0; j < 4; ++j) {
        acc[i][j] = MFMA16(ah[i], bh[j], acc[i][j]);
        acc[i][j] = MFMA16(ah[i], bl[j], acc[i][j]);
        acc[i][j] = MFMA16(al[i], bh[j], acc[i][j]);
      }
    __syncthreads();
  }

  // epilogue: C row = mB + r, col = n
#pragma unroll
  for (int i = 0; i < 4; ++i) {
    int mB = m0 + wr * 64 + i * 16 + lg * 4;
#pragma unroll
    for (int j = 0; j < 4; ++j) {
      int n = n0 + wc * 64 + j * 16 + lr;
      if constexpr (EPI == EPI_PART) {
        float* outp = (float*)out0 + (long)blockIdx.z * M * N;
#pragma unroll
        for (int r = 0; r < 4; ++r)
          outp[(long)(mB + r) * N + n] = acc[i][j][r];
      } else if constexpr (EPI == EPI_RELUHL) {
        float bs = bq_[n];
        short* oH = (short*)out0;
        short* oL = (short*)out1;
#pragma unroll
        for (int r = 0; r < 4; ++r) {
          float v = fmaxf(acc[i][j][r] + bs, 0.f);
          short hi = f2bf(v);
          long idx = (long)(mB + r) * N + n;
          oH[idx] = hi;
          oL[idx] = f2bf(v - bf2f(hi));
        }
      } else {  // EPI_QKV: q|k -> qk[S][2048] (q scaled QSCALE), v -> vT[1024][S]
        short* qko = (short*)out0;
        short* vto = (short*)out1;
        if (n < 1024) {
          float bs = bq_[n];
#pragma unroll
          for (int r = 0; r < 4; ++r)
            qko[(long)(mB + r) * 2048 + n] = f2bf((acc[i][j][r] + bs) * QSCALE);
        } else if (n < 2048) {
          float bs = bk_[n - 1024];
#pragma unroll
          for (int r = 0; r < 4; ++r)
            qko[(long)(mB + r) * 2048 + n] = f2bf(acc[i][j][r] + bs);
        } else {
          float bs = bv_[n - 2048];
          short4 pk;
          pk.x = f2bf(acc[i][j][0] + bs);
          pk.y = f2bf(acc[i][j][1] + bs);
          pk.z = f2bf(acc[i][j][2] + bs);
          pk.w = f2bf(acc[i][j][3] + bs);
          *(short4*)(vto + (long)(n - 2048) * S_ + mB) = pk;
        }
      }
    }
  }
}

// ---- flash attention: grid (S/128, H), 4 waves x 32 q-rows, KV tiles of 64.
// K/V tiles staged ONCE per block into LDS via global_load_lds (double-buffered,
// linear dest + pre-swizzled global source; XOR swizzle (row&7) on 16B granules
// kills the 16-way bank conflict of row-major [64][64] bf16 on ds_read_b128).
// S' = mfma(K,Q): lane holds q = lane&15, kv reg-local -> softmax is 15 fmax +
// 2 shfl_xor. P -> per-wave LDS -> ds_read_b128 B-frags. PV: O^T = mfma(V^T,P).
// Defer-max (THR=8, log2 domain), setprio on MFMA clusters.
__global__ __launch_bounds__(256, 2)
void attn_kernel(const short* __restrict__ qk, const short* __restrict__ vT,
                 short* __restrict__ attnH, short* __restrict__ attnL) {
  __shared__ short kvlds[2][2][4096];  // [buf][K/V][64 rows x 64 cols, swizzled]
  __shared__ short plds[4][32][72];    // per-wave P tile, stride 144B
  const int qt = blockIdx.x, h = blockIdx.y;
  const int tid = threadIdx.x;
  const int wave = tid >> 6, lane = tid & 63;
  const int lg = lane >> 4, lr = lane & 15;
  const int qrow0 = qt * 128 + wave * 32;

  const short* qh = qk + (long)qrow0 * 2048 + h * 64;
  const short* kh = qk + 1024 + h * 64;
  const short* vh = vT + (long)h * 64 * S_;

  // Q as B-operand frags: Q[qb*16+lr][di*32 + lg*8 + j]
  bf16x8_t qf[2][2];
#pragma unroll
  for (int qb = 0; qb < 2; ++qb)
#pragma unroll
    for (int di = 0; di < 2; ++di)
      qf[qb][di] = *(const bf16x8_t*)(qh + (long)(qb * 16 + lr) * 2048 + di * 32 + lg * 8);

  float m[2] = {-1e30f, -1e30f}, l[2] = {0.f, 0.f};
  f32x4_t o[2][4];
#pragma unroll
  for (int qb = 0; qb < 2; ++qb)
#pragma unroll
    for (int dd = 0; dd < 4; ++dd) o[qb][dd] = (f32x4_t){0.f, 0.f, 0.f, 0.f};

  // stage one 64x64 K tile + one 64x64 V tile into LDS buffer `buf`
  auto stage = [&](int buf, int kt) {
    short* kd = &kvlds[buf][0][0];
    short* vd = &kvlds[buf][1][0];
    const long kt64 = (long)kt * 64;
#pragma unroll
    for (int p = 0; p < 2; ++p) {
      int idx = tid + p * 256;
      int row = idx >> 3, c = idx & 7;
      int csw = (c ^ (row & 7)) << 3;  // inverse swizzle on global source
      async_copy16(kd + idx * 8, kh + (kt64 + row) * 2048 + csw);
      async_copy16(vd + idx * 8, vh + (long)row * S_ + kt64 + csw);
    }
  };

  stage(0, 0);
  __syncthreads();

  for (int kt = 0; kt < S_ / 64; ++kt) {
    const int buf = kt & 1;
    if (kt + 1 < S_ / 64) stage(buf ^ 1, kt + 1);

    const short* Kb = &kvlds[buf][0][0];
    const short* Vb = &kvlds[buf][1][0];

    // K frags from LDS (swizzled read)
    bf16x8_t kf[8];
#pragma unroll
    for (int kc = 0; kc < 4; ++kc)
#pragma unroll
      for (int di = 0; di < 2; ++di)
        kf[kc * 2 + di] = *(const bf16x8_t*)(
            Kb + ((kc * 16 + lr) << 6) + (((di * 4 + lg) ^ (lr & 7)) << 3));

    // S' = K.Q (swapped): 16 MFMA
    f32x4_t sacc[2][4];
#pragma unroll
    for (int qb = 0; qb < 2; ++qb)
#pragma unroll
      for (int kc = 0; kc < 4; ++kc) sacc[qb][kc] = (f32x4_t){0.f, 0.f, 0.f, 0.f};
    __builtin_amdgcn_s_setprio(1);
#pragma unroll
    for (int kc = 0; kc < 4; ++kc)
#pragma unroll
      for (int qb = 0; qb < 2; ++qb) {
        sacc[qb][kc] = MFMA16(kf[kc * 2 + 0], qf[qb][0], sacc[qb][kc]);
        sacc[qb][kc] = MFMA16(kf[kc * 2 + 1], qf[qb][1], sacc[qb][kc]);
      }
    __builtin_amdgcn_s_setprio(0);

    // softmax (per lane: one q-column, 16 kv values per qb)
#pragma unroll
    for (int qb = 0; qb < 2; ++qb) {
      float p01 = fmaxf(fmaxf(sacc[qb][0][0], sacc[qb][0][1]),
                        fmaxf(sacc[qb][0][2], sacc[qb][0][3]));
      float p23 = fmaxf(fmaxf(sacc[qb][1][0], sacc[qb][1][1]),
                        fmaxf(sacc[qb][1][2], sacc[qb][1][3]));
      float p45 = fmaxf(fmaxf(sacc[qb][2][0], sacc[qb][2][1]),
                        fmaxf(sacc[qb][2][2], sacc[qb][2][3]));
      float p67 = fmaxf(fmaxf(sacc[qb][3][0], sacc[qb][3][1]),
                        fmaxf(sacc[qb][3][2], sacc[qb][3][3]));
      float pmax = fmaxf(fmaxf(p01, p23), fmaxf(p45, p67));
      pmax = fmaxf(pmax, __shfl_xor(pmax, 16));
      pmax = fmaxf(pmax, __shfl_xor(pmax, 32));
      if (!__all(pmax <= m[qb] + 8.0f)) {  // defer-max: rescale rarely fires
        float ef = exp2f(m[qb] - pmax);
        m[qb] = pmax;
        l[qb] *= ef;
#pragma unroll
        for (int dd = 0; dd < 4; ++dd) o[qb][dd] *= ef;
      }
      float mq = m[qb];
      float rsum = 0.f;
#pragma unroll
      for (int kc = 0; kc < 4; ++kc) {
        float e0 = exp2f(sacc[qb][kc][0] - mq);
        float e1 = exp2f(sacc[qb][kc][1] - mq);
        float e2 = exp2f(sacc[qb][kc][2] - mq);
        float e3 = exp2f(sacc[qb][kc][3] - mq);
        rsum += (e0 + e1) + (e2 + e3);
        uint2 w;
        w.x = cvtpk_bf16(e0, e1);
        w.y = cvtpk_bf16(e2, e3);
        *(uint2*)&plds[wave][qb * 16 + lr][kc * 16 + lg * 4] = w;
      }
      rsum += __shfl_xor(rsum, 16);
      rsum += __shfl_xor(rsum, 32);
      l[qb] += rsum;
    }

    // P back as B-frags: P^T rows q=lr, kv contiguous
    bf16x8_t pb[2][2];
#pragma unroll
    for (int qb = 0; qb < 2; ++qb)
#pragma unroll
      for (int ks = 0; ks < 2; ++ks)
        pb[qb][ks] = *(const bf16x8_t*)&plds[wave][qb * 16 + lr][ks * 32 + lg * 8];

    // V frags from LDS (swizzled read)
    bf16x8_t vf[8];
#pragma unroll
    for (int dd = 0; dd < 4; ++dd)
#pragma unroll
      for (int ks = 0; ks < 2; ++ks)
        vf[dd * 2 + ks] = *(const bf16x8_t*)(
            Vb + ((dd * 16 + lr) << 6) + (((ks * 4 + lg) ^ (lr & 7)) << 3));

    // O^T += V^T . P : 16 MFMA
    __builtin_amdgcn_s_setprio(1);
#pragma unroll
    for (int dd = 0; dd < 4; ++dd)
#pragma unroll
      for (int qb = 0; qb < 2; ++qb) {
        o[qb][dd] = MFMA16(vf[dd * 2 + 0], pb[qb][0], o[qb][dd]);
        o[qb][dd] = MFMA16(vf[dd * 2 + 1], pb[qb][1], o[qb][dd]);
      }
    __builtin_amdgcn_s_setprio(0);

    __syncthreads();  // drains this wave's stage (vmcnt) + LDS reads, flips buffer
  }

  // normalize + store hi/lo (O^T: lane has 4 consecutive d per (qb,dd))
#pragma unroll
  for (int qb = 0; qb < 2; ++qb) {
    float inv = 1.0f / l[qb];
    int q = qrow0 + qb * 16 + lr;
#pragma unroll
    for (int dd = 0; dd < 4; ++dd) {
      long base = (long)q * D_ + h * 64 + dd * 16 + lg * 4;
      short4 hh, ll;
      float v0 = o[qb][dd][0] * inv; hh.x = f2bf(v0); ll.x = f2bf(v0 - bf2f(hh.x));
      float v1 = o[qb][dd][1] * inv; hh.y = f2bf(v1); ll.y = f2bf(v1 - bf2f(hh.y));
      float v2 = o[qb][dd][2] * inv; hh.z = f2bf(v2); ll.z = f2bf(v2 - bf2f(hh.z));
      float v3 = o[qb][dd][3] * inv; hh.w = f2bf(v3); ll.w = f2bf(v3 - bf2f(hh.w));
      *(short4*)(attnH + base) = hh;
      *(short4*)(attnL + base) = ll;
    }
  }
}

// ---- fused: x = pA + pB + res + bias; LayerNorm; optional hi/lo bf16 outputs
template<int WHL>
__global__ __launch_bounds__(256)
void ln_fused(const float* __restrict__ pA, const float* __restrict__ pB,
              const float* __restrict__ res, const float* __restrict__ bias,
              const float* __restrict__ g, const float* __restrict__ b,
              float* __restrict__ outF, short* __restrict__ outH,
              short* __restrict__ outL) {
  __shared__ float red[8];
  const int row = blockIdx.x, tid = threadIdx.x;
  const long base = (long)row * D_ + tid * 4;
  float4 a = *(const float4*)(pA + base);
  float4 c = *(const float4*)(pB + base);
  float4 rr = *(const float4*)(res + base);
  float4 bb = *(const float4*)(bias + tid * 4);
  float x0 = a.x + c.x + rr.x + bb.x;
  float x1v = a.y + c.y + rr.y + bb.y;
  float x2v = a.z + c.z + rr.z + bb.z;
  float x3v = a.w + c.w + rr.w + bb.w;
  float s = x0 + x1v + x2v + x3v;
  float s2 = x0 * x0 + x1v * x1v + x2v * x2v + x3v * x3v;
#pragma unroll
  for (int m = 1; m < 64; m <<= 1) {
    s += __shfl_xor(s, m);
    s2 += __shfl_xor(s2, m);
  }
  int wave = tid >> 6, lane = tid & 63;
  if (lane == 0) { red[wave * 2] = s; red[wave * 2 + 1] = s2; }
  __syncthreads();
  s = red[0] + red[2] + red[4] + red[6];
  s2 = red[1] + red[3] + red[5] + red[7];
  float mu = s * (1.f / D_);
  float var = s2 * (1.f / D_) - mu * mu;
  float rs = rsqrtf(var + 1e-5f);
  float4 gv = *(const float4*)(g + tid * 4);
  float4 bv = *(const float4*)(b + tid * 4);
  float y0 = (x0 - mu) * rs * gv.x + bv.x;
  float y1 = (x1v - mu) * rs * gv.y + bv.y;
  float y2 = (x2v - mu) * rs * gv.z + bv.z;
  float y3 = (x3v - mu) * rs * gv.w + bv.w;
  float4 ov = {y0, y1, y2, y3};
  *(float4*)(outF + base) = ov;
  if constexpr (WHL) {
    short4 hh, ll;
    hh.x = f2bf(y0); ll.x = f2bf(y0 - bf2f(hh.x));
    hh.y = f2bf(y1); ll.y = f2bf(y1 - bf2f(hh.y));
    hh.z = f2bf(y2); ll.z = f2bf(y2 - bf2f(hh.z));
    hh.w = f2bf(y3); ll.w = f2bf(y3 - bf2f(hh.w));
    *(short4*)(outH + base) = hh;
    *(short4*)(outL + base) = ll;
  }
}

extern "C" void kernel_launch(void* const* d_in, const int* in_sizes, int n_in,
                              void* d_out, int out_size, void* d_ws, size_t ws_size,
                              hipStream_t stream) {
  const float* src  = (const float*)d_in[0];
  const float* Wq   = (const float*)d_in[1];
  const float* bq   = (const float*)d_in[2];
  const float* Wk   = (const float*)d_in[3];
  const float* bk   = (const float*)d_in[4];
  const float* Wv   = (const float*)d_in[5];
  const float* bv   = (const float*)d_in[6];
  const float* Wo   = (const float*)d_in[7];
  const float* bo   = (const float*)d_in[8];
  const float* ln1g = (const float*)d_in[9];
  const float* ln1b = (const float*)d_in[10];
  const float* W1   = (const float*)d_in[11];
  const float* b1   = (const float*)d_in[12];
  const float* W2   = (const float*)d_in[13];
  const float* b2   = (const float*)d_in[14];
  const float* ln2g = (const float*)d_in[15];
  const float* ln2b = (const float*)d_in[16];
  float* out = (float*)d_out;

  const size_t SD = (size_t)S_ * D_;
  const size_t SF = (size_t)S_ * F_;

  char* w = (char*)d_ws;
  auto take = [&](size_t bytes) {
    char* p = w;
    w += (bytes + 255) & ~(size_t)255;
    return p;
  };
  // region A (aliased by W2 partials after attention is done):
  short* srcH  = (short*)take(SD * 2);
  short* srcL  = (short*)take(SD * 2);
  short* qkb   = (short*)take((size_t)S_ * 2048 * 2);
  short* vTb   = (short*)take((size_t)D_ * S_ * 2);
  // region B (aliased by Wo partials before W1 writes h1):
  short* h1H   = (short*)take(SF * 2);
  short* h1L   = (short*)take(SF * 2);
  // weights
  short* wqkvH = (short*)take((size_t)3072 * D_ * 2);
  short* wqkvL = (short*)take((size_t)3072 * D_ * 2);
  short* woH   = (short*)take((size_t)D_ * D_ * 2);
  short* woL   = (short*)take((size_t)D_ * D_ * 2);
  short* w1H   = (short*)take((size_t)F_ * D_ * 2);
  short* w1L   = (short*)take((size_t)F_ * D_ * 2);
  short* w2H   = (short*)take((size_t)D_ * F_ * 2);
  short* w2L   = (short*)take((size_t)D_ * F_ * 2);
  // activations
  short* attnH = (short*)take(SD * 2);
  short* attnL = (short*)take(SD * 2);
  float* x1    = (float*)take(SD * 4);
  short* x1H   = (short*)take(SD * 2);
  short* x1L   = (short*)take(SD * 2);

  float* partWo = (float*)h1H;   // 2*SD fp32 = 33.5 MB, fits in h1H (SF*2)
  float* partW2 = (float*)srcH;  // 2*SD fp32 spans srcH+srcL+qkb, all dead by then

  dim3 blk(256);

  // weight prep (transpose + hi/lo split); QKV into one [3072][1024] buffer
  prep_w<1><<<dim3(32, 32), blk, 0, stream>>>(Wq, wqkvH, wqkvL, D_, D_);
  prep_w<1><<<dim3(32, 32), blk, 0, stream>>>(Wk, wqkvH + (size_t)1024 * D_,
                                              wqkvL + (size_t)1024 * D_, D_, D_);
  prep_w<1><<<dim3(32, 32), blk, 0, stream>>>(Wv, wqkvH + (size_t)2048 * D_,
                                              wqkvL + (size_t)2048 * D_, D_, D_);
  prep_w<0><<<dim3(32, 32), blk, 0, stream>>>(Wo, woH, woL, D_, D_);
  prep_w<0><<<dim3(128, 32), blk, 0, stream>>>(W1, w1H, w1L, D_, F_);
  prep_w<0><<<dim3(32, 128), blk, 0, stream>>>(W2, w2H, w2L, F_, D_);

  // src -> hi/lo
  cvt_hl<<<dim3(4096), blk, 0, stream>>>(src, srcH, srcL);

  // fused QKV projection (q pre-scaled by QSCALE, v transposed per head)
  gemm_bf3<EPI_QKV, 1><<<dim3(32, 24), blk, 0, stream>>>(
      srcH, srcL, wqkvH, wqkvL, D_, S_, 3072, bq, bk, bv, qkb, vTb);

  // flash attention -> attn hi/lo [S][1024]
  attn_kernel<<<dim3(32, 16), blk, 0, stream>>>(qkb, vTb, attnH, attnL);

  // Wo projection, split-K=2 partials; LN1 fuses partials + src + bo
  gemm_bf3<EPI_PART, 2><<<dim3(32, 8, 2), blk, 0, stream>>>(
      attnH, attnL, woH, woL, D_, S_, D_, nullptr, nullptr, nullptr, partWo, nullptr);
  ln_fused<1><<<dim3(S_), blk, 0, stream>>>(partWo, partWo + SD, src, bo,
                                            ln1g, ln1b, x1, x1H, x1L);

  // FFN
  gemm_bf3<EPI_RELUHL, 1><<<dim3(32, 32), blk, 0, stream>>>(
      x1H, x1L, w1H, w1L, D_, S_, F_, b1, nullptr, nullptr, h1H, h1L);
  gemm_bf3<EPI_PART, 2><<<dim3(32, 8, 2), blk, 0, stream>>>(
      h1H, h1L, w2H, w2L, F_, S_, D_, nullptr, nullptr, nullptr, partW2, nullptr);
  ln_fused<0><<<dim3(S_), blk, 0, stream>>>(partW2, partW2 + SD, x1, b2,
                                            ln2g, ln2b, out, nullptr, nullptr);

  (void)in_sizes; (void)n_in; (void)out_size; (void)ws_size;
}

// Round 7
// 562.606 us; speedup vs baseline: 1.8598x; 1.1601x over previous
//
#include <hip/hip_runtime.h>
#include <hip/hip_bf16.h>

#define S_ 4096
#define D_ 1024
#define H_ 16
#define DK_ 64
#define F_ 4096

typedef short bf16x8_t __attribute__((ext_vector_type(8)));
typedef float f32x4_t __attribute__((ext_vector_type(4)));

#define MFMA16(a, b, c) __builtin_amdgcn_mfma_f32_16x16x32_bf16(a, b, c, 0, 0, 0)

// q-scale: 1/sqrt(64) * log2(e)  (softmax done in base-2)
#define QSCALE 0.1803368801111243f

__device__ __forceinline__ short f2bf(float f) {
  union { float f; unsigned u; } a; a.f = f;
  unsigned r = a.u + 0x7fffu + ((a.u >> 16) & 1u);
  return (short)(r >> 16);
}
__device__ __forceinline__ float bf2f(short s) {
  union { unsigned u; float f; } a; a.u = ((unsigned)(unsigned short)s) << 16;
  return a.f;
}
__device__ __forceinline__ unsigned cvtpk_bf16(float lo, float hi) {
  unsigned w;
  asm("v_cvt_pk_bf16_f32 %0, %1, %2" : "=v"(w) : "v"(lo), "v"(hi));
  return w;
}
__device__ __forceinline__ float exp2_fast(float x) {
  float r;
  asm("v_exp_f32 %0, %1" : "=v"(r) : "v"(x));
  return r;
}

__device__ __forceinline__ void async_copy16(short* ldsDst, const short* gSrc) {
  __builtin_amdgcn_global_load_lds(
      (const __attribute__((address_space(1))) unsigned int*)gSrc,
      (__attribute__((address_space(3))) unsigned int*)ldsDst, 16, 0, 0);
}

// ---- weight prep: fp32 [K][N] (flat) or [H][K][64] (head) -> single bf16 [N][K]
template<int HEADMODE>
__global__ __launch_bounds__(256)
void prep_w(const float* __restrict__ W, short* __restrict__ outHi, int K, int N) {
  __shared__ float t[32][33];
  int n0 = blockIdx.x * 32, k0 = blockIdx.y * 32;
  int tid = threadIdx.x;
  int cin = tid & 31, kin = tid >> 5;
#pragma unroll
  for (int i = 0; i < 4; ++i) {
    int k = kin + i * 8;
    int n = n0 + cin;
    long srcIdx;
    if (HEADMODE) srcIdx = ((long)(n >> 6) * K + (k0 + k)) * 64 + (n & 63);
    else          srcIdx = (long)(k0 + k) * N + n;
    t[k][cin] = W[srcIdx];
  }
  __syncthreads();
  int kout = tid & 31, cb = tid >> 5;
#pragma unroll
  for (int i = 0; i < 4; ++i) {
    int c = cb + i * 8;
    outHi[(long)(n0 + c) * K + (k0 + kout)] = f2bf(t[kout][c]);
  }
}

// ---- fp32 -> bf16 hi/lo elementwise
__global__ __launch_bounds__(256)
void cvt_hl(const float* __restrict__ x, short* __restrict__ h, short* __restrict__ l) {
  long i = ((long)blockIdx.x * 256 + threadIdx.x) * 4;
  float4 v = *(const float4*)(x + i);
  short4 hh, ll;
  hh.x = f2bf(v.x); ll.x = f2bf(v.x - bf2f(hh.x));
  hh.y = f2bf(v.y); ll.y = f2bf(v.y - bf2f(hh.y));
  hh.z = f2bf(v.z); ll.z = f2bf(v.z - bf2f(hh.z));
  hh.w = f2bf(v.w); ll.w = f2bf(v.w - bf2f(hh.w));
  *(short4*)(h + i) = hh;
  *(short4*)(l + i) = ll;
}

// ---- GEMM: C = (AH+AL)(fp32-split bf16) * B(single bf16, [N][K]) — 2 MFMA/pair
#define EPI_QKV 0
#define EPI_PART 1
#define EPI_RELUHL 2

template<int EPI, int SPLITK>
__global__ __launch_bounds__(256)
void gemm_bf3(const short* __restrict__ AH, const short* __restrict__ AL,
              const short* __restrict__ BH,
              int K, int M, int N,
              const float* __restrict__ bq_, const float* __restrict__ bk_,
              const float* __restrict__ bv_,
              void* __restrict__ out0, void* __restrict__ out1) {
  __shared__ short lds[12288];  // 24 KB: AH|AL|BH panels, each [128][32]
  const int m0 = blockIdx.x * 128, n0 = blockIdx.y * 128;
  const int tid = threadIdx.x;
  const int wave = tid >> 6, lane = tid & 63;
  const int wr = wave >> 1, wc = wave & 1;
  const int lg = lane >> 4, lr = lane & 15;
  const int kLen = (SPLITK > 1) ? (K / SPLITK) : K;
  const long kBase = (SPLITK > 1) ? (long)blockIdx.z * kLen : 0;
  const int nk = kLen >> 5;

  const short* gAH = AH + (long)m0 * K + kBase;
  const short* gAL = AL + (long)m0 * K + kBase;
  const short* gBH = BH + (long)n0 * K + kBase;

  f32x4_t acc[4][4];
#pragma unroll
  for (int i = 0; i < 4; ++i)
#pragma unroll
    for (int j = 0; j < 4; ++j)
      acc[i][j] = (f32x4_t){0.f, 0.f, 0.f, 0.f};

  for (int kt = 0; kt < nk; ++kt) {
    // stage 3 panels via global_load_lds (linear LDS, pre-swizzled global source)
#pragma unroll
    for (int p = 0; p < 6; ++p) {
      const short* gb = (p < 2) ? gAH : (p < 4) ? gAL : gBH;
      int w = ((p & 1) << 8) | tid;
      int row = w >> 2;
      int gsw = ((w & 3) ^ (row & 3)) << 3;  // XOR granule swizzle
      async_copy16(lds + (((p << 8) | tid) << 3),
                   gb + (long)row * K + (kt << 5) + gsw);
    }
    __syncthreads();
    bf16x8_t ah[4], al[4], bh[4];
#pragma unroll
    for (int f = 0; f < 4; ++f) {
      int ar = wr * 64 + f * 16 + lr;
      int ag = (lg ^ (ar & 3)) << 3;
      ah[f] = *(const bf16x8_t*)(lds + ar * 32 + ag);
      al[f] = *(const bf16x8_t*)(lds + 4096 + ar * 32 + ag);
      int br = wc * 64 + f * 16 + lr;
      int bg = (lg ^ (br & 3)) << 3;
      bh[f] = *(const bf16x8_t*)(lds + 8192 + br * 32 + bg);
    }
#pragma unroll
    for (int i = 0; i < 4; ++i)
#pragma unroll
      for (int j = 0; j < 4; ++j) {
        acc[i][j] = MFMA16(ah[i], bh[j], acc[i][j]);
        acc[i][j] = MFMA16(al[i], bh[j], acc[i][j]);
      }
    __syncthreads();
  }

  // epilogue: C row = mB + r, col = n
#pragma unroll
  for (int i = 0; i < 4; ++i) {
    int mB = m0 + wr * 64 + i * 16 + lg * 4;
#pragma unroll
    for (int j = 0; j < 4; ++j) {
      int n = n0 + wc * 64 + j * 16 + lr;
      if constexpr (EPI == EPI_PART) {
        float* outp = (float*)out0 + (long)blockIdx.z * M * N;
#pragma unroll
        for (int r = 0; r < 4; ++r)
          outp[(long)(mB + r) * N + n] = acc[i][j][r];
      } else if constexpr (EPI == EPI_RELUHL) {
        float bs = bq_[n];
        short* oH = (short*)out0;
        short* oL = (short*)out1;
#pragma unroll
        for (int r = 0; r < 4; ++r) {
          float v = fmaxf(acc[i][j][r] + bs, 0.f);
          short hi = f2bf(v);
          long idx = (long)(mB + r) * N + n;
          oH[idx] = hi;
          oL[idx] = f2bf(v - bf2f(hi));
        }
      } else {  // EPI_QKV: q|k -> qk[S][2048] (q scaled QSCALE), v -> vT[1024][S]
        short* qko = (short*)out0;
        short* vto = (short*)out1;
        if (n < 1024) {
          float bs = bq_[n];
#pragma unroll
          for (int r = 0; r < 4; ++r)
            qko[(long)(mB + r) * 2048 + n] = f2bf((acc[i][j][r] + bs) * QSCALE);
        } else if (n < 2048) {
          float bs = bk_[n - 1024];
#pragma unroll
          for (int r = 0; r < 4; ++r)
            qko[(long)(mB + r) * 2048 + n] = f2bf(acc[i][j][r] + bs);
        } else {
          float bs = bv_[n - 2048];
          short4 pk;
          pk.x = f2bf(acc[i][j][0] + bs);
          pk.y = f2bf(acc[i][j][1] + bs);
          pk.z = f2bf(acc[i][j][2] + bs);
          pk.w = f2bf(acc[i][j][3] + bs);
          *(short4*)(vto + (long)(n - 2048) * S_ + mB) = pk;
        }
      }
    }
  }
}

// ---- flash attention: grid (S/64, H), 4 waves x 16 q-rows, KV tiles of 64.
// K/V staged once per block in LDS (double-buffered global_load_lds, linear dest
// + pre-swizzled source; XOR (row&7) granule swizzle -> 2-way-free ds_read_b128).
// S' = mfma(K,Q): lane holds q = lane&15, kv reg-local -> softmax = 15 fmax +
// 2 shfl_xor + 16 v_exp. P -> per-wave LDS -> B-frags. PV: O^T = mfma(V^T,P).
// 1024 blocks, LDS 42KB -> 3 blocks/CU = 12 waves/CU.
__global__ __launch_bounds__(256, 3)
void attn_kernel(const short* __restrict__ qk, const short* __restrict__ vT,
                 short* __restrict__ attnH, short* __restrict__ attnL) {
  __shared__ short kvlds[2][2][4096];  // [buf][K/V][64 rows x 64 cols, swizzled]
  __shared__ short plds[4][16][72];    // per-wave P tile, stride 144B
  const int qt = blockIdx.x, h = blockIdx.y;
  const int tid = threadIdx.x;
  const int wave = tid >> 6, lane = tid & 63;
  const int lg = lane >> 4, lr = lane & 15;
  const int qrow0 = qt * 64 + wave * 16;

  const short* qh = qk + (long)qrow0 * 2048 + h * 64;
  const short* kh = qk + 1024 + h * 64;
  const short* vh = vT + (long)h * 64 * S_;

  // Q as B-operand frags: Q[lr][di*32 + lg*8 + j]
  bf16x8_t qf[2];
#pragma unroll
  for (int di = 0; di < 2; ++di)
    qf[di] = *(const bf16x8_t*)(qh + (long)lr * 2048 + di * 32 + lg * 8);

  float m = -1e30f, l = 0.f;
  f32x4_t o[4];
#pragma unroll
  for (int dd = 0; dd < 4; ++dd) o[dd] = (f32x4_t){0.f, 0.f, 0.f, 0.f};

  // stage one 64x64 K tile + one 64x64 V tile into LDS buffer `buf`
  auto stage = [&](int buf, int kt) {
    short* kd = &kvlds[buf][0][0];
    short* vd = &kvlds[buf][1][0];
    const long kt64 = (long)kt * 64;
#pragma unroll
    for (int p = 0; p < 2; ++p) {
      int idx = tid + p * 256;
      int row = idx >> 3, c = idx & 7;
      int csw = (c ^ (row & 7)) << 3;  // inverse swizzle on global source
      async_copy16(kd + idx * 8, kh + (kt64 + row) * 2048 + csw);
      async_copy16(vd + idx * 8, vh + (long)row * S_ + kt64 + csw);
    }
  };

  stage(0, 0);
  __syncthreads();

  for (int kt = 0; kt < S_ / 64; ++kt) {
    const int buf = kt & 1;
    if (kt + 1 < S_ / 64) stage(buf ^ 1, kt + 1);

    const short* Kb = &kvlds[buf][0][0];
    const short* Vb = &kvlds[buf][1][0];

    // K frags from LDS (swizzled read)
    bf16x8_t kf[8];
#pragma unroll
    for (int kc = 0; kc < 4; ++kc)
#pragma unroll
      for (int di = 0; di < 2; ++di)
        kf[kc * 2 + di] = *(const bf16x8_t*)(
            Kb + ((kc * 16 + lr) << 6) + (((di * 4 + lg) ^ (lr & 7)) << 3));

    // S' = K.Q (swapped): 8 MFMA
    f32x4_t sacc[4];
#pragma unroll
    for (int kc = 0; kc < 4; ++kc) sacc[kc] = (f32x4_t){0.f, 0.f, 0.f, 0.f};
    __builtin_amdgcn_s_setprio(1);
#pragma unroll
    for (int kc = 0; kc < 4; ++kc) {
      sacc[kc] = MFMA16(kf[kc * 2 + 0], qf[0], sacc[kc]);
      sacc[kc] = MFMA16(kf[kc * 2 + 1], qf[1], sacc[kc]);
    }
    __builtin_amdgcn_s_setprio(0);

    // softmax (per lane: one q-column, 16 kv values)
    {
      float p01 = fmaxf(fmaxf(sacc[0][0], sacc[0][1]), fmaxf(sacc[0][2], sacc[0][3]));
      float p23 = fmaxf(fmaxf(sacc[1][0], sacc[1][1]), fmaxf(sacc[1][2], sacc[1][3]));
      float p45 = fmaxf(fmaxf(sacc[2][0], sacc[2][1]), fmaxf(sacc[2][2], sacc[2][3]));
      float p67 = fmaxf(fmaxf(sacc[3][0], sacc[3][1]), fmaxf(sacc[3][2], sacc[3][3]));
      float pmax = fmaxf(fmaxf(p01, p23), fmaxf(p45, p67));
      pmax = fmaxf(pmax, __shfl_xor(pmax, 16));
      pmax = fmaxf(pmax, __shfl_xor(pmax, 32));
      if (!__all(pmax <= m + 8.0f)) {  // defer-max: rescale rarely fires
        float ef = exp2_fast(m - pmax);
        m = pmax;
        l *= ef;
#pragma unroll
        for (int dd = 0; dd < 4; ++dd) o[dd] *= ef;
      }
      float rsum = 0.f;
#pragma unroll
      for (int kc = 0; kc < 4; ++kc) {
        float e0 = exp2_fast(sacc[kc][0] - m);
        float e1 = exp2_fast(sacc[kc][1] - m);
        float e2 = exp2_fast(sacc[kc][2] - m);
        float e3 = exp2_fast(sacc[kc][3] - m);
        rsum += (e0 + e1) + (e2 + e3);
        uint2 w;
        w.x = cvtpk_bf16(e0, e1);
        w.y = cvtpk_bf16(e2, e3);
        *(uint2*)&plds[wave][lr][kc * 16 + lg * 4] = w;
      }
      rsum += __shfl_xor(rsum, 16);
      rsum += __shfl_xor(rsum, 32);
      l += rsum;
    }

    // P back as B-frags: rows q=lr, kv contiguous
    bf16x8_t pb[2];
#pragma unroll
    for (int ks = 0; ks < 2; ++ks)
      pb[ks] = *(const bf16x8_t*)&plds[wave][lr][ks * 32 + lg * 8];

    // V frags from LDS (swizzled read)
    bf16x8_t vf[8];
#pragma unroll
    for (int dd = 0; dd < 4; ++dd)
#pragma unroll
      for (int ks = 0; ks < 2; ++ks)
        vf[dd * 2 + ks] = *(const bf16x8_t*)(
            Vb + ((dd * 16 + lr) << 6) + (((ks * 4 + lg) ^ (lr & 7)) << 3));

    // O^T += V^T . P : 8 MFMA
    __builtin_amdgcn_s_setprio(1);
#pragma unroll
    for (int dd = 0; dd < 4; ++dd) {
      o[dd] = MFMA16(vf[dd * 2 + 0], pb[0], o[dd]);
      o[dd] = MFMA16(vf[dd * 2 + 1], pb[1], o[dd]);
    }
    __builtin_amdgcn_s_setprio(0);

    __syncthreads();  // drains stage (vmcnt) + LDS reads, flips buffer
  }

  // normalize + store hi/lo (O^T: lane has 4 consecutive d per dd)
  {
    float inv = 1.0f / l;
    int q = qrow0 + lr;
#pragma unroll
    for (int dd = 0; dd < 4; ++dd) {
      long base = (long)q * D_ + h * 64 + dd * 16 + lg * 4;
      short4 hh, ll;
      float v0 = o[dd][0] * inv; hh.x = f2bf(v0); ll.x = f2bf(v0 - bf2f(hh.x));
      float v1 = o[dd][1] * inv; hh.y = f2bf(v1); ll.y = f2bf(v1 - bf2f(hh.y));
      float v2 = o[dd][2] * inv; hh.z = f2bf(v2); ll.z = f2bf(v2 - bf2f(hh.z));
      float v3 = o[dd][3] * inv; hh.w = f2bf(v3); ll.w = f2bf(v3 - bf2f(hh.w));
      *(short4*)(attnH + base) = hh;
      *(short4*)(attnL + base) = ll;
    }
  }
}

// ---- fused: x = pA + pB + res + bias; LayerNorm; optional hi/lo bf16 outputs
template<int WHL>
__global__ __launch_bounds__(256)
void ln_fused(const float* __restrict__ pA, const float* __restrict__ pB,
              const float* __restrict__ res, const float* __restrict__ bias,
              const float* __restrict__ g, const float* __restrict__ b,
              float* __restrict__ outF, short* __restrict__ outH,
              short* __restrict__ outL) {
  __shared__ float red[8];
  const int row = blockIdx.x, tid = threadIdx.x;
  const long base = (long)row * D_ + tid * 4;
  float4 a = *(const float4*)(pA + base);
  float4 c = *(const float4*)(pB + base);
  float4 rr = *(const float4*)(res + base);
  float4 bb = *(const float4*)(bias + tid * 4);
  float x0 = a.x + c.x + rr.x + bb.x;
  float x1v = a.y + c.y + rr.y + bb.y;
  float x2v = a.z + c.z + rr.z + bb.z;
  float x3v = a.w + c.w + rr.w + bb.w;
  float s = x0 + x1v + x2v + x3v;
  float s2 = x0 * x0 + x1v * x1v + x2v * x2v + x3v * x3v;
#pragma unroll
  for (int m = 1; m < 64; m <<= 1) {
    s += __shfl_xor(s, m);
    s2 += __shfl_xor(s2, m);
  }
  int wave = tid >> 6, lane = tid & 63;
  if (lane == 0) { red[wave * 2] = s; red[wave * 2 + 1] = s2; }
  __syncthreads();
  s = red[0] + red[2] + red[4] + red[6];
  s2 = red[1] + red[3] + red[5] + red[7];
  float mu = s * (1.f / D_);
  float var = s2 * (1.f / D_) - mu * mu;
  float rs = rsqrtf(var + 1e-5f);
  float4 gv = *(const float4*)(g + tid * 4);
  float4 bv = *(const float4*)(b + tid * 4);
  float y0 = (x0 - mu) * rs * gv.x + bv.x;
  float y1 = (x1v - mu) * rs * gv.y + bv.y;
  float y2 = (x2v - mu) * rs * gv.z + bv.z;
  float y3 = (x3v - mu) * rs * gv.w + bv.w;
  float4 ov = {y0, y1, y2, y3};
  *(float4*)(outF + base) = ov;
  if constexpr (WHL) {
    short4 hh, ll;
    hh.x = f2bf(y0); ll.x = f2bf(y0 - bf2f(hh.x));
    hh.y = f2bf(y1); ll.y = f2bf(y1 - bf2f(hh.y));
    hh.z = f2bf(y2); ll.z = f2bf(y2 - bf2f(hh.z));
    hh.w = f2bf(y3); ll.w = f2bf(y3 - bf2f(hh.w));
    *(short4*)(outH + base) = hh;
    *(short4*)(outL + base) = ll;
  }
}

extern "C" void kernel_launch(void* const* d_in, const int* in_sizes, int n_in,
                              void* d_out, int out_size, void* d_ws, size_t ws_size,
                              hipStream_t stream) {
  const float* src  = (const float*)d_in[0];
  const float* Wq   = (const float*)d_in[1];
  const float* bq   = (const float*)d_in[2];
  const float* Wk   = (const float*)d_in[3];
  const float* bk   = (const float*)d_in[4];
  const float* Wv   = (const float*)d_in[5];
  const float* bv   = (const float*)d_in[6];
  const float* Wo   = (const float*)d_in[7];
  const float* bo   = (const float*)d_in[8];
  const float* ln1g = (const float*)d_in[9];
  const float* ln1b = (const float*)d_in[10];
  const float* W1   = (const float*)d_in[11];
  const float* b1   = (const float*)d_in[12];
  const float* W2   = (const float*)d_in[13];
  const float* b2   = (const float*)d_in[14];
  const float* ln2g = (const float*)d_in[15];
  const float* ln2b = (const float*)d_in[16];
  float* out = (float*)d_out;

  const size_t SD = (size_t)S_ * D_;
  const size_t SF = (size_t)S_ * F_;

  char* w = (char*)d_ws;
  auto take = [&](size_t bytes) {
    char* p = w;
    w += (bytes + 255) & ~(size_t)255;
    return p;
  };
  // region A (aliased by W2 partials after attention is done):
  short* srcH  = (short*)take(SD * 2);
  short* srcL  = (short*)take(SD * 2);
  short* qkb   = (short*)take((size_t)S_ * 2048 * 2);
  short* vTb   = (short*)take((size_t)D_ * S_ * 2);
  // region B (aliased by Wo partials before W1 writes h1):
  short* h1H   = (short*)take(SF * 2);
  short* h1L   = (short*)take(SF * 2);
  // weights (single bf16)
  short* wqkvH = (short*)take((size_t)3072 * D_ * 2);
  short* woH   = (short*)take((size_t)D_ * D_ * 2);
  short* w1H   = (short*)take((size_t)F_ * D_ * 2);
  short* w2H   = (short*)take((size_t)D_ * F_ * 2);
  // activations
  short* attnH = (short*)take(SD * 2);
  short* attnL = (short*)take(SD * 2);
  float* x1    = (float*)take(SD * 4);
  short* x1H   = (short*)take(SD * 2);
  short* x1L   = (short*)take(SD * 2);

  float* partWo = (float*)h1H;   // 2*SD fp32 = 33.5 MB, fits in h1H (SF*2)
  float* partW2 = (float*)srcH;  // 2*SD fp32 spans srcH+srcL+qkb, all dead by then

  dim3 blk(256);

  // weight prep (transpose, single bf16); QKV into one [3072][1024] buffer
  prep_w<1><<<dim3(32, 32), blk, 0, stream>>>(Wq, wqkvH, D_, D_);
  prep_w<1><<<dim3(32, 32), blk, 0, stream>>>(Wk, wqkvH + (size_t)1024 * D_, D_, D_);
  prep_w<1><<<dim3(32, 32), blk, 0, stream>>>(Wv, wqkvH + (size_t)2048 * D_, D_, D_);
  prep_w<0><<<dim3(32, 32), blk, 0, stream>>>(Wo, woH, D_, D_);
  prep_w<0><<<dim3(128, 32), blk, 0, stream>>>(W1, w1H, D_, F_);
  prep_w<0><<<dim3(32, 128), blk, 0, stream>>>(W2, w2H, F_, D_);

  // src -> hi/lo
  cvt_hl<<<dim3(4096), blk, 0, stream>>>(src, srcH, srcL);

  // fused QKV projection (q pre-scaled by QSCALE, v transposed per head)
  gemm_bf3<EPI_QKV, 1><<<dim3(32, 24), blk, 0, stream>>>(
      srcH, srcL, wqkvH, D_, S_, 3072, bq, bk, bv, qkb, vTb);

  // flash attention -> attn hi/lo [S][1024]
  attn_kernel<<<dim3(64, 16), blk, 0, stream>>>(qkb, vTb, attnH, attnL);

  // Wo projection, split-K=2 partials; LN1 fuses partials + src + bo
  gemm_bf3<EPI_PART, 2><<<dim3(32, 8, 2), blk, 0, stream>>>(
      attnH, attnL, woH, D_, S_, D_, nullptr, nullptr, nullptr, partWo, nullptr);
  ln_fused<1><<<dim3(S_), blk, 0, stream>>>(partWo, partWo + SD, src, bo,
                                            ln1g, ln1b, x1, x1H, x1L);

  // FFN
  gemm_bf3<EPI_RELUHL, 1><<<dim3(32, 32), blk, 0, stream>>>(
      x1H, x1L, w1H, D_, S_, F_, b1, nullptr, nullptr, h1H, h1L);
  gemm_bf3<EPI_PART, 2><<<dim3(32, 8, 2), blk, 0, stream>>>(
      h1H, h1L, w2H, F_, S_, D_, nullptr, nullptr, nullptr, partW2, nullptr);
  ln_fused<0><<<dim3(S_), blk, 0, stream>>>(partW2, partW2 + SD, x1, b2,
                                            ln2g, ln2b, out, nullptr, nullptr);

  (void)in_sizes; (void)n_in; (void)out_size; (void)ws_size;
}

// Round 8
// 486.371 us; speedup vs baseline: 2.1513x; 1.1567x over previous
//
#include <hip/hip_runtime.h>
#include <hip/hip_bf16.h>

#define S_ 4096
#define D_ 1024
#define H_ 16
#define DK_ 64
#define F_ 4096

typedef short bf16x8_t __attribute__((ext_vector_type(8)));
typedef float f32x4_t __attribute__((ext_vector_type(4)));

#define MFMA16(a, b, c) __builtin_amdgcn_mfma_f32_16x16x32_bf16(a, b, c, 0, 0, 0)

// q-scale: 1/sqrt(64) * log2(e)  (softmax done in base-2)
#define QSCALE 0.1803368801111243f

__device__ __forceinline__ short f2bf(float f) {
  union { float f; unsigned u; } a; a.f = f;
  unsigned r = a.u + 0x7fffu + ((a.u >> 16) & 1u);
  return (short)(r >> 16);
}
__device__ __forceinline__ float bf2f(short s) {
  union { unsigned u; float f; } a; a.u = ((unsigned)(unsigned short)s) << 16;
  return a.f;
}
__device__ __forceinline__ unsigned cvtpk_bf16(float lo, float hi) {
  unsigned w;
  asm("v_cvt_pk_bf16_f32 %0, %1, %2" : "=v"(w) : "v"(lo), "v"(hi));
  return w;
}
__device__ __forceinline__ float exp2_fast(float x) {
  float r;
  asm("v_exp_f32 %0, %1" : "=v"(r) : "v"(x));
  return r;
}

__device__ __forceinline__ void async_copy16(short* ldsDst, const short* gSrc) {
  __builtin_amdgcn_global_load_lds(
      (const __attribute__((address_space(1))) unsigned int*)gSrc,
      (__attribute__((address_space(3))) unsigned int*)ldsDst, 16, 0, 0);
}

// ---- weight prep: fp32 [K][N] (flat) or [H][K][64] (head) -> single bf16 [N][K]
template<int HEADMODE>
__global__ __launch_bounds__(256)
void prep_w(const float* __restrict__ W, short* __restrict__ outHi, int K, int N) {
  __shared__ float t[32][33];
  int n0 = blockIdx.x * 32, k0 = blockIdx.y * 32;
  int tid = threadIdx.x;
  int cin = tid & 31, kin = tid >> 5;
#pragma unroll
  for (int i = 0; i < 4; ++i) {
    int k = kin + i * 8;
    int n = n0 + cin;
    long srcIdx;
    if (HEADMODE) srcIdx = ((long)(n >> 6) * K + (k0 + k)) * 64 + (n & 63);
    else          srcIdx = (long)(k0 + k) * N + n;
    t[k][cin] = W[srcIdx];
  }
  __syncthreads();
  int kout = tid & 31, cb = tid >> 5;
#pragma unroll
  for (int i = 0; i < 4; ++i) {
    int c = cb + i * 8;
    outHi[(long)(n0 + c) * K + (k0 + kout)] = f2bf(t[kout][c]);
  }
}

// ---- fp32 -> single bf16 elementwise
__global__ __launch_bounds__(256)
void cvt_b(const float* __restrict__ x, short* __restrict__ h) {
  long i = ((long)blockIdx.x * 256 + threadIdx.x) * 4;
  float4 v = *(const float4*)(x + i);
  short4 hh;
  hh.x = f2bf(v.x);
  hh.y = f2bf(v.y);
  hh.z = f2bf(v.z);
  hh.w = f2bf(v.w);
  *(short4*)(h + i) = hh;
}

// ---- GEMM, 128x128 tile, BK=32, global_load_lds staging, swizzled LDS.
// AHL=0: A single bf16 (16 MFMA/kt, 16KB LDS). AHL=1: A hi/lo (32 MFMA, 24KB).
#define EPI_QKV 0
#define EPI_PART 1
#define EPI_RELUHL 2

template<int AHL, int EPI, int SPLITK>
__global__ __launch_bounds__(256)
void gemm_bf(const short* __restrict__ AH, const short* __restrict__ AL,
             const short* __restrict__ BH,
             int K, int M, int N,
             const float* __restrict__ bq_, const float* __restrict__ bk_,
             const float* __restrict__ bv_,
             void* __restrict__ out0, void* __restrict__ out1) {
  constexpr int NP = AHL ? 3 : 2;
  __shared__ short lds[NP * 4096];  // panels: A[H] | (AL) | B, each [128][32]
  const int m0 = blockIdx.x * 128, n0 = blockIdx.y * 128;
  const int tid = threadIdx.x;
  const int wave = tid >> 6, lane = tid & 63;
  const int wr = wave >> 1, wc = wave & 1;
  const int lg = lane >> 4, lr = lane & 15;
  const int kLen = (SPLITK > 1) ? (K / SPLITK) : K;
  const long kBase = (SPLITK > 1) ? (long)blockIdx.z * kLen : 0;
  const int nk = kLen >> 5;

  const short* gAH = AH + (long)m0 * K + kBase;
  const short* gAL = AHL ? (AL + (long)m0 * K + kBase) : nullptr;
  const short* gBH = BH + (long)n0 * K + kBase;

  f32x4_t acc[4][4];
#pragma unroll
  for (int i = 0; i < 4; ++i)
#pragma unroll
    for (int j = 0; j < 4; ++j)
      acc[i][j] = (f32x4_t){0.f, 0.f, 0.f, 0.f};

  for (int kt = 0; kt < nk; ++kt) {
    // stage panels via global_load_lds (linear LDS, pre-swizzled global source)
#pragma unroll
    for (int p = 0; p < 2 * NP; ++p) {
      const short* gb;
      if constexpr (AHL) gb = (p < 2) ? gAH : (p < 4) ? gAL : gBH;
      else               gb = (p < 2) ? gAH : gBH;
      int w = ((p & 1) << 8) | tid;
      int row = w >> 2;
      int gsw = ((w & 3) ^ (row & 3)) << 3;  // XOR granule swizzle
      async_copy16(lds + (((p << 8) | tid) << 3),
                   gb + (long)row * K + (kt << 5) + gsw);
    }
    __syncthreads();
    bf16x8_t ah[4], al[4], bh[4];
    constexpr int BOFF = AHL ? 8192 : 4096;
#pragma unroll
    for (int f = 0; f < 4; ++f) {
      int ar = wr * 64 + f * 16 + lr;
      int ag = (lg ^ (ar & 3)) << 3;
      ah[f] = *(const bf16x8_t*)(lds + ar * 32 + ag);
      if constexpr (AHL) al[f] = *(const bf16x8_t*)(lds + 4096 + ar * 32 + ag);
      int br = wc * 64 + f * 16 + lr;
      int bg = (lg ^ (br & 3)) << 3;
      bh[f] = *(const bf16x8_t*)(lds + BOFF + br * 32 + bg);
    }
#pragma unroll
    for (int i = 0; i < 4; ++i)
#pragma unroll
      for (int j = 0; j < 4; ++j) {
        acc[i][j] = MFMA16(ah[i], bh[j], acc[i][j]);
        if constexpr (AHL) acc[i][j] = MFMA16(al[i], bh[j], acc[i][j]);
      }
    __syncthreads();
  }

  // epilogue: C row = mB + r, col = n
#pragma unroll
  for (int i = 0; i < 4; ++i) {
    int mB = m0 + wr * 64 + i * 16 + lg * 4;
#pragma unroll
    for (int j = 0; j < 4; ++j) {
      int n = n0 + wc * 64 + j * 16 + lr;
      if constexpr (EPI == EPI_PART) {
        float* outp = (float*)out0 + (long)blockIdx.z * M * N;
#pragma unroll
        for (int r = 0; r < 4; ++r)
          outp[(long)(mB + r) * N + n] = acc[i][j][r];
      } else if constexpr (EPI == EPI_RELUHL) {
        float bs = bq_[n];
        short* oH = (short*)out0;
        short* oL = (short*)out1;
#pragma unroll
        for (int r = 0; r < 4; ++r) {
          float v = fmaxf(acc[i][j][r] + bs, 0.f);
          short hi = f2bf(v);
          long idx = (long)(mB + r) * N + n;
          oH[idx] = hi;
          oL[idx] = f2bf(v - bf2f(hi));
        }
      } else {  // EPI_QKV: q|k -> qk[S][2048] (q scaled QSCALE), v -> vT[1024][S]
        short* qko = (short*)out0;
        short* vto = (short*)out1;
        if (n < 1024) {
          float bs = bq_[n];
#pragma unroll
          for (int r = 0; r < 4; ++r)
            qko[(long)(mB + r) * 2048 + n] = f2bf((acc[i][j][r] + bs) * QSCALE);
        } else if (n < 2048) {
          float bs = bk_[n - 1024];
#pragma unroll
          for (int r = 0; r < 4; ++r)
            qko[(long)(mB + r) * 2048 + n] = f2bf(acc[i][j][r] + bs);
        } else {
          float bs = bv_[n - 2048];
          short4 pk;
          pk.x = f2bf(acc[i][j][0] + bs);
          pk.y = f2bf(acc[i][j][1] + bs);
          pk.z = f2bf(acc[i][j][2] + bs);
          pk.w = f2bf(acc[i][j][3] + bs);
          *(short4*)(vto + (long)(n - 2048) * S_ + mB) = pk;
        }
      }
    }
  }
}

// ---- flash attention: grid (S/128, H), 4 waves x 32 q-rows, KV tiles of 64.
// K/V staged once per block in LDS (double-buffered global_load_lds, linear dest
// + pre-swizzled source; XOR (row&7) granule swizzle on ds_read_b128).
// S' = mfma(K,Q): lane holds q = lane&15, kv reg-local -> softmax = reg fmax +
// 2 shfl_xor + v_exp. P -> per-wave LDS -> B-frags. PV: O^T = mfma(V^T,P).
__global__ __launch_bounds__(256, 2)
void attn_kernel(const short* __restrict__ qk, const short* __restrict__ vT,
                 short* __restrict__ attnB) {
  __shared__ short kvlds[2][2][4096];  // [buf][K/V][64 rows x 64 cols, swizzled]
  __shared__ short plds[4][32][72];    // per-wave P tile, stride 144B
  const int qt = blockIdx.x, h = blockIdx.y;
  const int tid = threadIdx.x;
  const int wave = tid >> 6, lane = tid & 63;
  const int lg = lane >> 4, lr = lane & 15;
  const int qrow0 = qt * 128 + wave * 32;

  const short* qh = qk + (long)qrow0 * 2048 + h * 64;
  const short* kh = qk + 1024 + h * 64;
  const short* vh = vT + (long)h * 64 * S_;

  // Q as B-operand frags: Q[qb*16+lr][di*32 + lg*8 + j]
  bf16x8_t qf[2][2];
#pragma unroll
  for (int qb = 0; qb < 2; ++qb)
#pragma unroll
    for (int di = 0; di < 2; ++di)
      qf[qb][di] = *(const bf16x8_t*)(qh + (long)(qb * 16 + lr) * 2048 + di * 32 + lg * 8);

  float m[2] = {-1e30f, -1e30f}, l[2] = {0.f, 0.f};
  f32x4_t o[2][4];
#pragma unroll
  for (int qb = 0; qb < 2; ++qb)
#pragma unroll
    for (int dd = 0; dd < 4; ++dd) o[qb][dd] = (f32x4_t){0.f, 0.f, 0.f, 0.f};

  // stage one 64x64 K tile + one 64x64 V tile into LDS buffer `buf`
  auto stage = [&](int buf, int kt) {
    short* kd = &kvlds[buf][0][0];
    short* vd = &kvlds[buf][1][0];
    const long kt64 = (long)kt * 64;
#pragma unroll
    for (int p = 0; p < 2; ++p) {
      int idx = tid + p * 256;
      int row = idx >> 3, c = idx & 7;
      int csw = (c ^ (row & 7)) << 3;  // inverse swizzle on global source
      async_copy16(kd + idx * 8, kh + (kt64 + row) * 2048 + csw);
      async_copy16(vd + idx * 8, vh + (long)row * S_ + kt64 + csw);
    }
  };

  stage(0, 0);
  __syncthreads();

  for (int kt = 0; kt < S_ / 64; ++kt) {
    const int buf = kt & 1;
    if (kt + 1 < S_ / 64) stage(buf ^ 1, kt + 1);

    const short* Kb = &kvlds[buf][0][0];
    const short* Vb = &kvlds[buf][1][0];

    // K frags from LDS (swizzled read)
    bf16x8_t kf[8];
#pragma unroll
    for (int kc = 0; kc < 4; ++kc)
#pragma unroll
      for (int di = 0; di < 2; ++di)
        kf[kc * 2 + di] = *(const bf16x8_t*)(
            Kb + ((kc * 16 + lr) << 6) + (((di * 4 + lg) ^ (lr & 7)) << 3));

    // S' = K.Q (swapped): 16 MFMA
    f32x4_t sacc[2][4];
#pragma unroll
    for (int qb = 0; qb < 2; ++qb)
#pragma unroll
      for (int kc = 0; kc < 4; ++kc) sacc[qb][kc] = (f32x4_t){0.f, 0.f, 0.f, 0.f};
    __builtin_amdgcn_s_setprio(1);
#pragma unroll
    for (int kc = 0; kc < 4; ++kc)
#pragma unroll
      for (int qb = 0; qb < 2; ++qb) {
        sacc[qb][kc] = MFMA16(kf[kc * 2 + 0], qf[qb][0], sacc[qb][kc]);
        sacc[qb][kc] = MFMA16(kf[kc * 2 + 1], qf[qb][1], sacc[qb][kc]);
      }
    __builtin_amdgcn_s_setprio(0);

    // softmax (per lane: one q-column, 16 kv values per qb)
#pragma unroll
    for (int qb = 0; qb < 2; ++qb) {
      float p01 = fmaxf(fmaxf(sacc[qb][0][0], sacc[qb][0][1]),
                        fmaxf(sacc[qb][0][2], sacc[qb][0][3]));
      float p23 = fmaxf(fmaxf(sacc[qb][1][0], sacc[qb][1][1]),
                        fmaxf(sacc[qb][1][2], sacc[qb][1][3]));
      float p45 = fmaxf(fmaxf(sacc[qb][2][0], sacc[qb][2][1]),
                        fmaxf(sacc[qb][2][2], sacc[qb][2][3]));
      float p67 = fmaxf(fmaxf(sacc[qb][3][0], sacc[qb][3][1]),
                        fmaxf(sacc[qb][3][2], sacc[qb][3][3]));
      float pmax = fmaxf(fmaxf(p01, p23), fmaxf(p45, p67));
      pmax = fmaxf(pmax, __shfl_xor(pmax, 16));
      pmax = fmaxf(pmax, __shfl_xor(pmax, 32));
      if (!__all(pmax <= m[qb] + 8.0f)) {  // defer-max: rescale rarely fires
        float ef = exp2_fast(m[qb] - pmax);
        m[qb] = pmax;
        l[qb] *= ef;
#pragma unroll
        for (int dd = 0; dd < 4; ++dd) o[qb][dd] *= ef;
      }
      float mq = m[qb];
      float rsum = 0.f;
#pragma unroll
      for (int kc = 0; kc < 4; ++kc) {
        float e0 = exp2_fast(sacc[qb][kc][0] - mq);
        float e1 = exp2_fast(sacc[qb][kc][1] - mq);
        float e2 = exp2_fast(sacc[qb][kc][2] - mq);
        float e3 = exp2_fast(sacc[qb][kc][3] - mq);
        rsum += (e0 + e1) + (e2 + e3);
        uint2 w;
        w.x = cvtpk_bf16(e0, e1);
        w.y = cvtpk_bf16(e2, e3);
        *(uint2*)&plds[wave][qb * 16 + lr][kc * 16 + lg * 4] = w;
      }
      rsum += __shfl_xor(rsum, 16);
      rsum += __shfl_xor(rsum, 32);
      l[qb] += rsum;
    }

    // P back as B-frags: rows q, kv contiguous
    bf16x8_t pb[2][2];
#pragma unroll
    for (int qb = 0; qb < 2; ++qb)
#pragma unroll
      for (int ks = 0; ks < 2; ++ks)
        pb[qb][ks] = *(const bf16x8_t*)&plds[wave][qb * 16 + lr][ks * 32 + lg * 8];

    // V frags from LDS (swizzled read)
    bf16x8_t vf[8];
#pragma unroll
    for (int dd = 0; dd < 4; ++dd)
#pragma unroll
      for (int ks = 0; ks < 2; ++ks)
        vf[dd * 2 + ks] = *(const bf16x8_t*)(
            Vb + ((dd * 16 + lr) << 6) + (((ks * 4 + lg) ^ (lr & 7)) << 3));

    // O^T += V^T . P : 16 MFMA
    __builtin_amdgcn_s_setprio(1);
#pragma unroll
    for (int dd = 0; dd < 4; ++dd)
#pragma unroll
      for (int qb = 0; qb < 2; ++qb) {
        o[qb][dd] = MFMA16(vf[dd * 2 + 0], pb[qb][0], o[qb][dd]);
        o[qb][dd] = MFMA16(vf[dd * 2 + 1], pb[qb][1], o[qb][dd]);
      }
    __builtin_amdgcn_s_setprio(0);

    __syncthreads();  // drains stage (vmcnt) + LDS reads, flips buffer
  }

  // normalize + store single bf16 (O^T: lane has 4 consecutive d per (qb,dd))
#pragma unroll
  for (int qb = 0; qb < 2; ++qb) {
    float inv = 1.0f / l[qb];
    int q = qrow0 + qb * 16 + lr;
#pragma unroll
    for (int dd = 0; dd < 4; ++dd) {
      long base = (long)q * D_ + h * 64 + dd * 16 + lg * 4;
      short4 hh;
      hh.x = f2bf(o[qb][dd][0] * inv);
      hh.y = f2bf(o[qb][dd][1] * inv);
      hh.z = f2bf(o[qb][dd][2] * inv);
      hh.w = f2bf(o[qb][dd][3] * inv);
      *(short4*)(attnB + base) = hh;
    }
  }
}

// ---- fused: x = pA + pB + res + bias; LayerNorm; optional single bf16 output
template<int WB>
__global__ __launch_bounds__(256)
void ln_fused(const float* __restrict__ pA, const float* __restrict__ pB,
              const float* __restrict__ res, const float* __restrict__ bias,
              const float* __restrict__ g, const float* __restrict__ b,
              float* __restrict__ outF, short* __restrict__ outB) {
  __shared__ float red[8];
  const int row = blockIdx.x, tid = threadIdx.x;
  const long base = (long)row * D_ + tid * 4;
  float4 a = *(const float4*)(pA + base);
  float4 c = *(const float4*)(pB + base);
  float4 rr = *(const float4*)(res + base);
  float4 bb = *(const float4*)(bias + tid * 4);
  float x0 = a.x + c.x + rr.x + bb.x;
  float x1v = a.y + c.y + rr.y + bb.y;
  float x2v = a.z + c.z + rr.z + bb.z;
  float x3v = a.w + c.w + rr.w + bb.w;
  float s = x0 + x1v + x2v + x3v;
  float s2 = x0 * x0 + x1v * x1v + x2v * x2v + x3v * x3v;
#pragma unroll
  for (int m = 1; m < 64; m <<= 1) {
    s += __shfl_xor(s, m);
    s2 += __shfl_xor(s2, m);
  }
  int wave = tid >> 6, lane = tid & 63;
  if (lane == 0) { red[wave * 2] = s; red[wave * 2 + 1] = s2; }
  __syncthreads();
  s = red[0] + red[2] + red[4] + red[6];
  s2 = red[1] + red[3] + red[5] + red[7];
  float mu = s * (1.f / D_);
  float var = s2 * (1.f / D_) - mu * mu;
  float rs = rsqrtf(var + 1e-5f);
  float4 gv = *(const float4*)(g + tid * 4);
  float4 bv = *(const float4*)(b + tid * 4);
  float y0 = (x0 - mu) * rs * gv.x + bv.x;
  float y1 = (x1v - mu) * rs * gv.y + bv.y;
  float y2 = (x2v - mu) * rs * gv.z + bv.z;
  float y3 = (x3v - mu) * rs * gv.w + bv.w;
  float4 ov = {y0, y1, y2, y3};
  *(float4*)(outF + base) = ov;
  if constexpr (WB) {
    short4 hh;
    hh.x = f2bf(y0);
    hh.y = f2bf(y1);
    hh.z = f2bf(y2);
    hh.w = f2bf(y3);
    *(short4*)(outB + base) = hh;
  }
}

extern "C" void kernel_launch(void* const* d_in, const int* in_sizes, int n_in,
                              void* d_out, int out_size, void* d_ws, size_t ws_size,
                              hipStream_t stream) {
  const float* src  = (const float*)d_in[0];
  const float* Wq   = (const float*)d_in[1];
  const float* bq   = (const float*)d_in[2];
  const float* Wk   = (const float*)d_in[3];
  const float* bk   = (const float*)d_in[4];
  const float* Wv   = (const float*)d_in[5];
  const float* bv   = (const float*)d_in[6];
  const float* Wo   = (const float*)d_in[7];
  const float* bo   = (const float*)d_in[8];
  const float* ln1g = (const float*)d_in[9];
  const float* ln1b = (const float*)d_in[10];
  const float* W1   = (const float*)d_in[11];
  const float* b1   = (const float*)d_in[12];
  const float* W2   = (const float*)d_in[13];
  const float* b2   = (const float*)d_in[14];
  const float* ln2g = (const float*)d_in[15];
  const float* ln2b = (const float*)d_in[16];
  float* out = (float*)d_out;

  const size_t SD = (size_t)S_ * D_;
  const size_t SF = (size_t)S_ * F_;

  char* w = (char*)d_ws;
  auto take = [&](size_t bytes) {
    char* p = w;
    w += (bytes + 255) & ~(size_t)255;
    return p;
  };
  // region A (aliased by W2 partials after attention is done):
  short* srcB  = (short*)take(SD * 2);
  short* qkb   = (short*)take((size_t)S_ * 2048 * 2);
  short* vTb   = (short*)take((size_t)D_ * S_ * 2);
  // region B (aliased by Wo partials before W1 writes h1):
  short* h1H   = (short*)take(SF * 2);
  short* h1L   = (short*)take(SF * 2);
  // weights (single bf16)
  short* wqkvB = (short*)take((size_t)3072 * D_ * 2);
  short* woB   = (short*)take((size_t)D_ * D_ * 2);
  short* w1B   = (short*)take((size_t)F_ * D_ * 2);
  short* w2B   = (short*)take((size_t)D_ * F_ * 2);
  // activations
  short* attnB = (short*)take(SD * 2);
  float* x1    = (float*)take(SD * 4);
  short* x1B   = (short*)take(SD * 2);

  float* partWo = (float*)h1H;   // 2*SD fp32 = 33.5 MB, fits in h1H (SF*2)
  float* partW2 = (float*)srcB;  // 2*SD fp32 spans srcB+qkb+vTb, all dead by then

  dim3 blk(256);

  // weight prep (transpose, single bf16); QKV into one [3072][1024] buffer
  prep_w<1><<<dim3(32, 32), blk, 0, stream>>>(Wq, wqkvB, D_, D_);
  prep_w<1><<<dim3(32, 32), blk, 0, stream>>>(Wk, wqkvB + (size_t)1024 * D_, D_, D_);
  prep_w<1><<<dim3(32, 32), blk, 0, stream>>>(Wv, wqkvB + (size_t)2048 * D_, D_, D_);
  prep_w<0><<<dim3(32, 32), blk, 0, stream>>>(Wo, woB, D_, D_);
  prep_w<0><<<dim3(128, 32), blk, 0, stream>>>(W1, w1B, D_, F_);
  prep_w<0><<<dim3(32, 128), blk, 0, stream>>>(W2, w2B, F_, D_);

  // src -> single bf16
  cvt_b<<<dim3(4096), blk, 0, stream>>>(src, srcB);

  // fused QKV projection (A single; q pre-scaled by QSCALE, v transposed per head)
  gemm_bf<0, EPI_QKV, 1><<<dim3(32, 24), blk, 0, stream>>>(
      srcB, nullptr, wqkvB, D_, S_, 3072, bq, bk, bv, qkb, vTb);

  // flash attention -> attn single bf16 [S][1024]
  attn_kernel<<<dim3(32, 16), blk, 0, stream>>>(qkb, vTb, attnB);

  // Wo projection (A single), split-K=2 partials; LN1 fuses partials + src + bo
  gemm_bf<0, EPI_PART, 2><<<dim3(32, 8, 2), blk, 0, stream>>>(
      attnB, nullptr, woB, D_, S_, D_, nullptr, nullptr, nullptr, partWo, nullptr);
  ln_fused<1><<<dim3(S_), blk, 0, stream>>>(partWo, partWo + SD, src, bo,
                                            ln1g, ln1b, x1, x1B);

  // FFN: W1 (A single) -> h1 hi/lo; W2 (A hi/lo, K=4096) -> partials
  gemm_bf<0, EPI_RELUHL, 1><<<dim3(32, 32), blk, 0, stream>>>(
      x1B, nullptr, w1B, D_, S_, F_, b1, nullptr, nullptr, h1H, h1L);
  gemm_bf<1, EPI_PART, 2><<<dim3(32, 8, 2), blk, 0, stream>>>(
      h1H, h1L, w2B, F_, S_, D_, nullptr, nullptr, nullptr, partW2, nullptr);
  ln_fused<0><<<dim3(S_), blk, 0, stream>>>(partW2, partW2 + SD, x1, b2,
                                            ln2g, ln2b, out, nullptr);

  (void)in_sizes; (void)n_in; (void)out_size; (void)ws_size;
}

// Round 9
// 443.008 us; speedup vs baseline: 2.3618x; 1.0979x over previous
//
#include <hip/hip_runtime.h>
#include <hip/hip_bf16.h>

#define S_ 4096
#define D_ 1024
#define H_ 16
#define DK_ 64
#define F_ 4096

typedef short bf16x8_t __attribute__((ext_vector_type(8)));
typedef float f32x4_t __attribute__((ext_vector_type(4)));

#define MFMA16(a, b, c) __builtin_amdgcn_mfma_f32_16x16x32_bf16(a, b, c, 0, 0, 0)

// q-scale: 1/sqrt(64) * log2(e)  (softmax done in base-2)
#define QSCALE 0.1803368801111243f

__device__ __forceinline__ short f2bf(float f) {
  union { float f; unsigned u; } a; a.f = f;
  unsigned r = a.u + 0x7fffu + ((a.u >> 16) & 1u);
  return (short)(r >> 16);
}
__device__ __forceinline__ float bf2f(short s) {
  union { unsigned u; float f; } a; a.u = ((unsigned)(unsigned short)s) << 16;
  return a.f;
}
__device__ __forceinline__ unsigned cvtpk_bf16(float lo, float hi) {
  unsigned w;
  asm("v_cvt_pk_bf16_f32 %0, %1, %2" : "=v"(w) : "v"(lo), "v"(hi));
  return w;
}
__device__ __forceinline__ float exp2_fast(float x) {
  float r;
  asm("v_exp_f32 %0, %1" : "=v"(r) : "v"(x));
  return r;
}

__device__ __forceinline__ void async_copy16(short* ldsDst, const short* gSrc) {
  __builtin_amdgcn_global_load_lds(
      (const __attribute__((address_space(1))) unsigned int*)gSrc,
      (__attribute__((address_space(3))) unsigned int*)ldsDst, 16, 0, 0);
}

// ---- weight prep: fp32 [K][N] (flat) or [H][K][64] (head) -> single bf16 [N][K]
template<int HEADMODE>
__global__ __launch_bounds__(256)
void prep_w(const float* __restrict__ W, short* __restrict__ outHi, int K, int N) {
  __shared__ float t[32][33];
  int n0 = blockIdx.x * 32, k0 = blockIdx.y * 32;
  int tid = threadIdx.x;
  int cin = tid & 31, kin = tid >> 5;
#pragma unroll
  for (int i = 0; i < 4; ++i) {
    int k = kin + i * 8;
    int n = n0 + cin;
    long srcIdx;
    if (HEADMODE) srcIdx = ((long)(n >> 6) * K + (k0 + k)) * 64 + (n & 63);
    else          srcIdx = (long)(k0 + k) * N + n;
    t[k][cin] = W[srcIdx];
  }
  __syncthreads();
  int kout = tid & 31, cb = tid >> 5;
#pragma unroll
  for (int i = 0; i < 4; ++i) {
    int c = cb + i * 8;
    outHi[(long)(n0 + c) * K + (k0 + kout)] = f2bf(t[kout][c]);
  }
}

// ---- fp32 -> single bf16 elementwise
__global__ __launch_bounds__(256)
void cvt_b(const float* __restrict__ x, short* __restrict__ h) {
  long i = ((long)blockIdx.x * 256 + threadIdx.x) * 4;
  float4 v = *(const float4*)(x + i);
  short4 hh;
  hh.x = f2bf(v.x);
  hh.y = f2bf(v.y);
  hh.z = f2bf(v.z);
  hh.w = f2bf(v.w);
  *(short4*)(h + i) = hh;
}

// ---- GEMM, 128x128 tile, BK=32, global_load_lds staging, swizzled LDS.
#define EPI_QKV 0
#define EPI_PART 1
#define EPI_RELUB 2

template<int EPI, int SPLITK>
__global__ __launch_bounds__(256)
void gemm_bf(const short* __restrict__ AH, const short* __restrict__ BH,
             int K, int M, int N,
             const float* __restrict__ bq_, const float* __restrict__ bk_,
             const float* __restrict__ bv_,
             void* __restrict__ out0, void* __restrict__ out1) {
  __shared__ short lds[8192];  // 16 KB: A | B panels, each [128][32]
  const int m0 = blockIdx.x * 128, n0 = blockIdx.y * 128;
  const int tid = threadIdx.x;
  const int wave = tid >> 6, lane = tid & 63;
  const int wr = wave >> 1, wc = wave & 1;
  const int lg = lane >> 4, lr = lane & 15;
  const int kLen = (SPLITK > 1) ? (K / SPLITK) : K;
  const long kBase = (SPLITK > 1) ? (long)blockIdx.z * kLen : 0;
  const int nk = kLen >> 5;

  const short* gAH = AH + (long)m0 * K + kBase;
  const short* gBH = BH + (long)n0 * K + kBase;

  f32x4_t acc[4][4];
#pragma unroll
  for (int i = 0; i < 4; ++i)
#pragma unroll
    for (int j = 0; j < 4; ++j)
      acc[i][j] = (f32x4_t){0.f, 0.f, 0.f, 0.f};

  for (int kt = 0; kt < nk; ++kt) {
    // stage panels via global_load_lds (linear LDS, pre-swizzled global source)
#pragma unroll
    for (int p = 0; p < 4; ++p) {
      const short* gb = (p < 2) ? gAH : gBH;
      int w = ((p & 1) << 8) | tid;
      int row = w >> 2;
      int gsw = ((w & 3) ^ (row & 3)) << 3;  // XOR granule swizzle
      async_copy16(lds + (((p << 8) | tid) << 3),
                   gb + (long)row * K + (kt << 5) + gsw);
    }
    __syncthreads();
    bf16x8_t ah[4], bh[4];
#pragma unroll
    for (int f = 0; f < 4; ++f) {
      int ar = wr * 64 + f * 16 + lr;
      int ag = (lg ^ (ar & 3)) << 3;
      ah[f] = *(const bf16x8_t*)(lds + ar * 32 + ag);
      int br = wc * 64 + f * 16 + lr;
      int bg = (lg ^ (br & 3)) << 3;
      bh[f] = *(const bf16x8_t*)(lds + 4096 + br * 32 + bg);
    }
#pragma unroll
    for (int i = 0; i < 4; ++i)
#pragma unroll
      for (int j = 0; j < 4; ++j)
        acc[i][j] = MFMA16(ah[i], bh[j], acc[i][j]);
    __syncthreads();
  }

  // epilogue: C row = mB + r, col = n
#pragma unroll
  for (int i = 0; i < 4; ++i) {
    int mB = m0 + wr * 64 + i * 16 + lg * 4;
#pragma unroll
    for (int j = 0; j < 4; ++j) {
      int n = n0 + wc * 64 + j * 16 + lr;
      if constexpr (EPI == EPI_PART) {
        float* outp = (float*)out0 + (long)blockIdx.z * M * N;
#pragma unroll
        for (int r = 0; r < 4; ++r)
          outp[(long)(mB + r) * N + n] = acc[i][j][r];
      } else if constexpr (EPI == EPI_RELUB) {
        float bs = bq_[n];
        short* oB = (short*)out0;
#pragma unroll
        for (int r = 0; r < 4; ++r)
          oB[(long)(mB + r) * N + n] = f2bf(fmaxf(acc[i][j][r] + bs, 0.f));
      } else {  // EPI_QKV: q|k -> qk[S][2048] (q scaled QSCALE), v -> vT[1024][S]
        short* qko = (short*)out0;
        short* vto = (short*)out1;
        if (n < 1024) {
          float bs = bq_[n];
#pragma unroll
          for (int r = 0; r < 4; ++r)
            qko[(long)(mB + r) * 2048 + n] = f2bf((acc[i][j][r] + bs) * QSCALE);
        } else if (n < 2048) {
          float bs = bk_[n - 1024];
#pragma unroll
          for (int r = 0; r < 4; ++r)
            qko[(long)(mB + r) * 2048 + n] = f2bf(acc[i][j][r] + bs);
        } else {
          float bs = bv_[n - 2048];
          short4 pk;
          pk.x = f2bf(acc[i][j][0] + bs);
          pk.y = f2bf(acc[i][j][1] + bs);
          pk.z = f2bf(acc[i][j][2] + bs);
          pk.w = f2bf(acc[i][j][3] + bs);
          *(short4*)(vto + (long)(n - 2048) * S_ + mB) = pk;
        }
      }
    }
  }
}

// ---- flash attention, software-pipelined: grid (S/128, H), 4 waves x 32 q-rows.
// Per segment: issue QK(t+1) MFMAs + stage(t+2) + V(t+1) ds_reads FIRST (all
// independent), then softmax(t) VALU chain overlaps the matrix/mem pipes, then
// PV(t). Double-buffered LDS K/V tiles; double-buffered sacc/vf register state
// (named A/B, static indexing). K/V staged via global_load_lds, pre-swizzled
// source + XOR(row&7) granule swizzle on ds_read_b128.
__global__ __launch_bounds__(256, 2)
void attn_kernel(const short* __restrict__ qk, const short* __restrict__ vT,
                 short* __restrict__ attnB) {
  __shared__ short kvlds[2][2][4096];  // [buf][K/V][64x64 swizzled]
  __shared__ short plds[4][32][72];    // per-wave P tile, stride 144B
  const int qt = blockIdx.x, h = blockIdx.y;
  const int tid = threadIdx.x;
  const int wave = tid >> 6, lane = tid & 63;
  const int lg = lane >> 4, lr = lane & 15;
  const int qrow0 = qt * 128 + wave * 32;

  const short* qh = qk + (long)qrow0 * 2048 + h * 64;
  const short* kh = qk + 1024 + h * 64;
  const short* vh = vT + (long)h * 64 * S_;

  bf16x8_t qf[2][2];
#pragma unroll
  for (int qb = 0; qb < 2; ++qb)
#pragma unroll
    for (int di = 0; di < 2; ++di)
      qf[qb][di] = *(const bf16x8_t*)(qh + (long)(qb * 16 + lr) * 2048 + di * 32 + lg * 8);

  float m[2] = {-1e30f, -1e30f}, l[2] = {0.f, 0.f};
  f32x4_t o[2][4];
#pragma unroll
  for (int qb = 0; qb < 2; ++qb)
#pragma unroll
    for (int dd = 0; dd < 4; ++dd) o[qb][dd] = (f32x4_t){0.f, 0.f, 0.f, 0.f};

  auto stage = [&](int buf, int kt) {
    short* kd = &kvlds[buf][0][0];
    short* vd = &kvlds[buf][1][0];
    const long kt64 = (long)kt * 64;
#pragma unroll
    for (int p = 0; p < 2; ++p) {
      int idx = tid + p * 256;
      int row = idx >> 3, c = idx & 7;
      int csw = (c ^ (row & 7)) << 3;  // inverse swizzle on global source
      async_copy16(kd + idx * 8, kh + (kt64 + row) * 2048 + csw);
      async_copy16(vd + idx * 8, vh + (long)row * S_ + kt64 + csw);
    }
  };

  auto qkStep = [&](int kt, f32x4_t (&sacc)[2][4]) {
    const short* Kb = &kvlds[kt & 1][0][0];
    bf16x8_t kf[8];
#pragma unroll
    for (int kc = 0; kc < 4; ++kc)
#pragma unroll
      for (int di = 0; di < 2; ++di)
        kf[kc * 2 + di] = *(const bf16x8_t*)(
            Kb + ((kc * 16 + lr) << 6) + (((di * 4 + lg) ^ (lr & 7)) << 3));
#pragma unroll
    for (int qb = 0; qb < 2; ++qb)
#pragma unroll
      for (int kc = 0; kc < 4; ++kc) sacc[qb][kc] = (f32x4_t){0.f, 0.f, 0.f, 0.f};
    __builtin_amdgcn_s_setprio(1);
#pragma unroll
    for (int kc = 0; kc < 4; ++kc)
#pragma unroll
      for (int qb = 0; qb < 2; ++qb) {
        sacc[qb][kc] = MFMA16(kf[kc * 2 + 0], qf[qb][0], sacc[qb][kc]);
        sacc[qb][kc] = MFMA16(kf[kc * 2 + 1], qf[qb][1], sacc[qb][kc]);
      }
    __builtin_amdgcn_s_setprio(0);
  };

  auto vload = [&](int kt, bf16x8_t (&vf)[8]) {
    const short* Vb = &kvlds[kt & 1][1][0];
#pragma unroll
    for (int dd = 0; dd < 4; ++dd)
#pragma unroll
      for (int ks = 0; ks < 2; ++ks)
        vf[dd * 2 + ks] = *(const bf16x8_t*)(
            Vb + ((dd * 16 + lr) << 6) + (((ks * 4 + lg) ^ (lr & 7)) << 3));
  };

  auto smStep = [&](f32x4_t (&sacc)[2][4]) {
#pragma unroll
    for (int qb = 0; qb < 2; ++qb) {
      float p01 = fmaxf(fmaxf(sacc[qb][0][0], sacc[qb][0][1]),
                        fmaxf(sacc[qb][0][2], sacc[qb][0][3]));
      float p23 = fmaxf(fmaxf(sacc[qb][1][0], sacc[qb][1][1]),
                        fmaxf(sacc[qb][1][2], sacc[qb][1][3]));
      float p45 = fmaxf(fmaxf(sacc[qb][2][0], sacc[qb][2][1]),
                        fmaxf(sacc[qb][2][2], sacc[qb][2][3]));
      float p67 = fmaxf(fmaxf(sacc[qb][3][0], sacc[qb][3][1]),
                        fmaxf(sacc[qb][3][2], sacc[qb][3][3]));
      float pmax = fmaxf(fmaxf(p01, p23), fmaxf(p45, p67));
      pmax = fmaxf(pmax, __shfl_xor(pmax, 16));
      pmax = fmaxf(pmax, __shfl_xor(pmax, 32));
      if (!__all(pmax <= m[qb] + 8.0f)) {  // defer-max
        float ef = exp2_fast(m[qb] - pmax);
        m[qb] = pmax;
        l[qb] *= ef;
#pragma unroll
        for (int dd = 0; dd < 4; ++dd) o[qb][dd] *= ef;
      }
      float mq = m[qb];
      float rsum = 0.f;
#pragma unroll
      for (int kc = 0; kc < 4; ++kc) {
        float e0 = exp2_fast(sacc[qb][kc][0] - mq);
        float e1 = exp2_fast(sacc[qb][kc][1] - mq);
        float e2 = exp2_fast(sacc[qb][kc][2] - mq);
        float e3 = exp2_fast(sacc[qb][kc][3] - mq);
        rsum += (e0 + e1) + (e2 + e3);
        uint2 w;
        w.x = cvtpk_bf16(e0, e1);
        w.y = cvtpk_bf16(e2, e3);
        *(uint2*)&plds[wave][qb * 16 + lr][kc * 16 + lg * 4] = w;
      }
      rsum += __shfl_xor(rsum, 16);
      rsum += __shfl_xor(rsum, 32);
      l[qb] += rsum;
    }
  };

  auto pvStep = [&](bf16x8_t (&vf)[8]) {
    bf16x8_t pb[2][2];
#pragma unroll
    for (int qb = 0; qb < 2; ++qb)
#pragma unroll
      for (int ks = 0; ks < 2; ++ks)
        pb[qb][ks] = *(const bf16x8_t*)&plds[wave][qb * 16 + lr][ks * 32 + lg * 8];
    __builtin_amdgcn_s_setprio(1);
#pragma unroll
    for (int dd = 0; dd < 4; ++dd)
#pragma unroll
      for (int qb = 0; qb < 2; ++qb) {
        o[qb][dd] = MFMA16(vf[dd * 2 + 0], pb[qb][0], o[qb][dd]);
        o[qb][dd] = MFMA16(vf[dd * 2 + 1], pb[qb][1], o[qb][dd]);
      }
    __builtin_amdgcn_s_setprio(0);
  };

  f32x4_t saccA[2][4], saccB[2][4];
  bf16x8_t vfA[8], vfB[8];
  constexpr int NT = S_ / 64;

  // prologue: tile0 staged+consumed-to-regs, tile1 staged
  stage(0, 0);
  __syncthreads();
  qkStep(0, saccA);
  stage(1, 1);
  vload(0, vfA);
  __syncthreads();

  for (int kt = 0; kt < NT; kt += 2) {
    // even half: independent work for tile kt+1 first, then SM/PV of tile kt
    qkStep(kt + 1, saccB);
    if (kt + 2 < NT) stage(kt & 1, kt + 2);
    vload(kt + 1, vfB);
    smStep(saccA);
    pvStep(vfA);
    __syncthreads();

    // odd half
    if (kt + 2 < NT) {
      qkStep(kt + 2, saccA);
      if (kt + 3 < NT) stage((kt + 1) & 1, kt + 3);
      vload(kt + 2, vfA);
    }
    smStep(saccB);
    pvStep(vfB);
    __syncthreads();
  }

  // normalize + store single bf16 (O^T: lane has 4 consecutive d per (qb,dd))
#pragma unroll
  for (int qb = 0; qb < 2; ++qb) {
    float inv = 1.0f / l[qb];
    int q = qrow0 + qb * 16 + lr;
#pragma unroll
    for (int dd = 0; dd < 4; ++dd) {
      long base = (long)q * D_ + h * 64 + dd * 16 + lg * 4;
      short4 hh;
      hh.x = f2bf(o[qb][dd][0] * inv);
      hh.y = f2bf(o[qb][dd][1] * inv);
      hh.z = f2bf(o[qb][dd][2] * inv);
      hh.w = f2bf(o[qb][dd][3] * inv);
      *(short4*)(attnB + base) = hh;
    }
  }
}

// ---- fused: x = pA + pB + res + bias; LayerNorm; optional single bf16 output
template<int WB>
__global__ __launch_bounds__(256)
void ln_fused(const float* __restrict__ pA, const float* __restrict__ pB,
              const float* __restrict__ res, const float* __restrict__ bias,
              const float* __restrict__ g, const float* __restrict__ b,
              float* __restrict__ outF, short* __restrict__ outB) {
  __shared__ float red[8];
  const int row = blockIdx.x, tid = threadIdx.x;
  const long base = (long)row * D_ + tid * 4;
  float4 a = *(const float4*)(pA + base);
  float4 c = *(const float4*)(pB + base);
  float4 rr = *(const float4*)(res + base);
  float4 bb = *(const float4*)(bias + tid * 4);
  float x0 = a.x + c.x + rr.x + bb.x;
  float x1v = a.y + c.y + rr.y + bb.y;
  float x2v = a.z + c.z + rr.z + bb.z;
  float x3v = a.w + c.w + rr.w + bb.w;
  float s = x0 + x1v + x2v + x3v;
  float s2 = x0 * x0 + x1v * x1v + x2v * x2v + x3v * x3v;
#pragma unroll
  for (int m = 1; m < 64; m <<= 1) {
    s += __shfl_xor(s, m);
    s2 += __shfl_xor(s2, m);
  }
  int wave = tid >> 6, lane = tid & 63;
  if (lane == 0) { red[wave * 2] = s; red[wave * 2 + 1] = s2; }
  __syncthreads();
  s = red[0] + red[2] + red[4] + red[6];
  s2 = red[1] + red[3] + red[5] + red[7];
  float mu = s * (1.f / D_);
  float var = s2 * (1.f / D_) - mu * mu;
  float rs = rsqrtf(var + 1e-5f);
  float4 gv = *(const float4*)(g + tid * 4);
  float4 bv = *(const float4*)(b + tid * 4);
  float y0 = (x0 - mu) * rs * gv.x + bv.x;
  float y1 = (x1v - mu) * rs * gv.y + bv.y;
  float y2 = (x2v - mu) * rs * gv.z + bv.z;
  float y3 = (x3v - mu) * rs * gv.w + bv.w;
  float4 ov = {y0, y1, y2, y3};
  *(float4*)(outF + base) = ov;
  if constexpr (WB) {
    short4 hh;
    hh.x = f2bf(y0);
    hh.y = f2bf(y1);
    hh.z = f2bf(y2);
    hh.w = f2bf(y3);
    *(short4*)(outB + base) = hh;
  }
}

extern "C" void kernel_launch(void* const* d_in, const int* in_sizes, int n_in,
                              void* d_out, int out_size, void* d_ws, size_t ws_size,
                              hipStream_t stream) {
  const float* src  = (const float*)d_in[0];
  const float* Wq   = (const float*)d_in[1];
  const float* bq   = (const float*)d_in[2];
  const float* Wk   = (const float*)d_in[3];
  const float* bk   = (const float*)d_in[4];
  const float* Wv   = (const float*)d_in[5];
  const float* bv   = (const float*)d_in[6];
  const float* Wo   = (const float*)d_in[7];
  const float* bo   = (const float*)d_in[8];
  const float* ln1g = (const float*)d_in[9];
  const float* ln1b = (const float*)d_in[10];
  const float* W1   = (const float*)d_in[11];
  const float* b1   = (const float*)d_in[12];
  const float* W2   = (const float*)d_in[13];
  const float* b2   = (const float*)d_in[14];
  const float* ln2g = (const float*)d_in[15];
  const float* ln2b = (const float*)d_in[16];
  float* out = (float*)d_out;

  const size_t SD = (size_t)S_ * D_;
  const size_t SF = (size_t)S_ * F_;

  char* w = (char*)d_ws;
  auto take = [&](size_t bytes) {
    char* p = w;
    w += (bytes + 255) & ~(size_t)255;
    return p;
  };
  // region A (aliased by W2 partials after attention is done):
  short* srcB  = (short*)take(SD * 2);
  short* qkb   = (short*)take((size_t)S_ * 2048 * 2);
  short* vTb   = (short*)take((size_t)D_ * S_ * 2);
  // region B (Wo partials; then h1):
  short* h1B   = (short*)take(SF * 2);
  // weights (single bf16)
  short* wqkvB = (short*)take((size_t)3072 * D_ * 2);
  short* woB   = (short*)take((size_t)D_ * D_ * 2);
  short* w1B   = (short*)take((size_t)F_ * D_ * 2);
  short* w2B   = (short*)take((size_t)D_ * F_ * 2);
  // activations
  short* attnB = (short*)take(SD * 2);
  float* x1    = (float*)take(SD * 4);
  short* x1B   = (short*)take(SD * 2);

  float* partWo = (float*)h1B;   // 2*SD fp32 = 33.5 MB = SF*2 exactly
  float* partW2 = (float*)srcB;  // 2*SD fp32 spans srcB+qkb+vTb, all dead by then

  dim3 blk(256);

  // weight prep (transpose, single bf16); QKV into one [3072][1024] buffer
  prep_w<1><<<dim3(32, 32), blk, 0, stream>>>(Wq, wqkvB, D_, D_);
  prep_w<1><<<dim3(32, 32), blk, 0, stream>>>(Wk, wqkvB + (size_t)1024 * D_, D_, D_);
  prep_w<1><<<dim3(32, 32), blk, 0, stream>>>(Wv, wqkvB + (size_t)2048 * D_, D_, D_);
  prep_w<0><<<dim3(32, 32), blk, 0, stream>>>(Wo, woB, D_, D_);
  prep_w<0><<<dim3(128, 32), blk, 0, stream>>>(W1, w1B, D_, F_);
  prep_w<0><<<dim3(32, 128), blk, 0, stream>>>(W2, w2B, F_, D_);

  // src -> single bf16
  cvt_b<<<dim3(4096), blk, 0, stream>>>(src, srcB);

  // fused QKV projection (q pre-scaled by QSCALE, v transposed per head)
  gemm_bf<EPI_QKV, 1><<<dim3(32, 24), blk, 0, stream>>>(
      srcB, wqkvB, D_, S_, 3072, bq, bk, bv, qkb, vTb);

  // flash attention -> attn single bf16 [S][1024]
  attn_kernel<<<dim3(32, 16), blk, 0, stream>>>(qkb, vTb, attnB);

  // Wo projection, split-K=2 partials; LN1 fuses partials + src + bo
  gemm_bf<EPI_PART, 2><<<dim3(32, 8, 2), blk, 0, stream>>>(
      attnB, woB, D_, S_, D_, nullptr, nullptr, nullptr, partWo, nullptr);
  ln_fused<1><<<dim3(S_), blk, 0, stream>>>(partWo, partWo + SD, src, bo,
                                            ln1g, ln1b, x1, x1B);

  // FFN: W1 -> h1 single bf16; W2 (K=4096) -> partials
  gemm_bf<EPI_RELUB, 1><<<dim3(32, 32), blk, 0, stream>>>(
      x1B, w1B, D_, S_, F_, b1, nullptr, nullptr, h1B, nullptr);
  gemm_bf<EPI_PART, 2><<<dim3(32, 8, 2), blk, 0, stream>>>(
      h1B, w2B, F_, S_, D_, nullptr, nullptr, nullptr, partW2, nullptr);
  ln_fused<0><<<dim3(S_), blk, 0, stream>>>(partW2, partW2 + SD, x1, b2,
                                            ln2g, ln2b, out, nullptr);

  (void)in_sizes; (void)n_in; (void)out_size; (void)ws_size;
}